// Round 1
// baseline (1457.553 us; speedup 1.0000x reference)
//
#include <hip/hip_runtime.h>
#include <hip/hip_bf16.h>
#include <stdint.h>
#include <stddef.h>

#define NN 50000
#define NE 800000

typedef __attribute__((ext_vector_type(8))) __bf16 bf16x8;
typedef __attribute__((ext_vector_type(4))) float  f32x4;

static __device__ __forceinline__ float ldf(const float* p)  { return *p; }
static __device__ __forceinline__ float ldf(const __bf16* p) { return (float)(*p); }

// ---------------- CSR build ----------------
__global__ __launch_bounds__(256) void k_count(const int* __restrict__ v, int* __restrict__ cnt) {
    int i = blockIdx.x * 256 + threadIdx.x;
    int stride = gridDim.x * 256;
    for (; i < NE; i += stride) atomicAdd(&cnt[v[i]], 1);
}

__global__ __launch_bounds__(1024) void k_scan(const int* __restrict__ cnt,
                                               int* __restrict__ off,
                                               int* __restrict__ cur) {
    __shared__ int sh[1024];
    const int T = 1024;
    const int C = (NN + T - 1) / T;   // 49
    int t = threadIdx.x;
    int base = t * C;
    int s = 0;
    for (int j = 0; j < C; ++j) {
        int idx = base + j;
        if (idx < NN) s += cnt[idx];
    }
    sh[t] = s;
    __syncthreads();
    for (int d = 1; d < T; d <<= 1) {
        int val = (t >= d) ? sh[t - d] : 0;
        __syncthreads();
        sh[t] += val;
        __syncthreads();
    }
    int run = sh[t] - s;   // exclusive prefix of this thread's chunk
    for (int j = 0; j < C; ++j) {
        int idx = base + j;
        if (idx < NN) {
            off[idx] = run; cur[idx] = run;
            run += cnt[idx];
        }
    }
    if (t == T - 1) off[NN] = sh[T - 1];
}

__global__ __launch_bounds__(256) void k_fill(const int* __restrict__ v,
                                              int* __restrict__ cur,
                                              int* __restrict__ eid) {
    int i = blockIdx.x * 256 + threadIdx.x;
    int stride = gridDim.x * 256;
    for (; i < NE; i += stride) {
        int pos = atomicAdd(&cur[v[i]], 1);
        eid[pos] = i;
    }
}

// ---------------- f32 -> bf16 convert ----------------
__global__ __launch_bounds__(256) void k_cvt(const float* __restrict__ src,
                                             __bf16* __restrict__ dst, int n) {
    int i = blockIdx.x * 256 + threadIdx.x;
    int stride = gridDim.x * 256;
    for (; i < n; i += stride) dst[i] = (__bf16)src[i];
}

// ---------------- mean aggregation + concat; writes X[n][384] bf16 ----------------
template <typename TN, typename TE>
__global__ __launch_bounds__(256) void k_agg(const TN* __restrict__ nf,
                                             const TE* __restrict__ ef,
                                             const int* __restrict__ u,
                                             const int* __restrict__ eid,
                                             const int* __restrict__ off,
                                             __bf16* __restrict__ X) {
    int n = blockIdx.x;
    int t = threadIdx.x;            // 0..255
    int p0 = off[n], p1 = off[n + 1];
    float acc = 0.f;
    if (t < 128) {
        for (int p = p0; p < p1; ++p) {
            int e  = eid[p];
            int su = u[e];
            acc += ldf(&nf[(size_t)su * 128 + t]);
        }
    } else {
        int tt = t - 128;
        for (int p = p0; p < p1; ++p) {
            int e = eid[p];
            acc += ldf(&ef[(size_t)e * 128 + tt]);
        }
    }
    float inv = (p1 > p0) ? (1.f / (float)(p1 - p0)) : 0.f;
    X[(size_t)n * 384 + 128 + t] = (__bf16)(acc * inv);
    if (t < 128) X[(size_t)n * 384 + t] = (__bf16)ldf(&nf[(size_t)n * 128 + t]);
}

// ---------------- node MLP: Y = relu(X[M,K] @ W[128,K]^T + b) ----------------
// wave computes 32(M) x 128(N); block = 4 waves = 128 rows.
template <int K, bool SF32, bool SBF>
__global__ __launch_bounds__(256) void k_mlp_node(const __bf16* __restrict__ A,
                                                  const __bf16* __restrict__ W,
                                                  const float* __restrict__ bias,
                                                  __bf16* __restrict__ Ybf,
                                                  float* __restrict__ Yf,
                                                  int M) {
    const int wave = threadIdx.x >> 6;
    const int lane = threadIdx.x & 63;
    const int m0 = blockIdx.x * 128 + wave * 32;
    const int lr = lane & 15;
    const int kg = lane >> 4;

    f32x4 acc[2][8];
#pragma unroll
    for (int i = 0; i < 2; ++i)
#pragma unroll
        for (int j = 0; j < 8; ++j) acc[i][j] = (f32x4){0.f, 0.f, 0.f, 0.f};

    int ra0 = m0 + lr;      if (ra0 > M - 1) ra0 = M - 1;
    int ra1 = m0 + 16 + lr; if (ra1 > M - 1) ra1 = M - 1;
    const __bf16* pa0 = A + (size_t)ra0 * K + 8 * kg;
    const __bf16* pa1 = A + (size_t)ra1 * K + 8 * kg;
    const __bf16* pw  = W + (size_t)lr * K + 8 * kg;

#pragma unroll 4
    for (int k0 = 0; k0 < K; k0 += 32) {
        bf16x8 a0 = *(const bf16x8*)(pa0 + k0);
        bf16x8 a1 = *(const bf16x8*)(pa1 + k0);
#pragma unroll
        for (int j = 0; j < 8; ++j) {
            bf16x8 b = *(const bf16x8*)(pw + (size_t)j * 16 * K + k0);
            acc[0][j] = __builtin_amdgcn_mfma_f32_16x16x32_bf16(a0, b, acc[0][j], 0, 0, 0);
            acc[1][j] = __builtin_amdgcn_mfma_f32_16x16x32_bf16(a1, b, acc[1][j], 0, 0, 0);
        }
    }

#pragma unroll
    for (int j = 0; j < 8; ++j) {
        int col = j * 16 + lr;
        float bb = bias[col];
#pragma unroll
        for (int i = 0; i < 2; ++i) {
#pragma unroll
            for (int r = 0; r < 4; ++r) {
                int row = m0 + i * 16 + kg * 4 + r;
                if (row < M) {
                    float val = fmaxf(acc[i][j][r] + bb, 0.f);
                    if (SBF)  Ybf[(size_t)row * 128 + col] = (__bf16)val;
                    if (SF32) Yf[(size_t)row * 128 + col]  = val;
                }
            }
        }
    }
}

// ---------------- edge MLP: Y[e] = relu([H[u[e]],H[v[e]]] @ W[128,256]^T + b) ----------------
template <bool SF32>
__global__ __launch_bounds__(256) void k_mlp_edge(const __bf16* __restrict__ H,
                                                  const int* __restrict__ u,
                                                  const int* __restrict__ v,
                                                  const __bf16* __restrict__ W,
                                                  const float* __restrict__ bias,
                                                  __bf16* __restrict__ Ybf,
                                                  float* __restrict__ Yf) {
    const int wave = threadIdx.x >> 6;
    const int lane = threadIdx.x & 63;
    const int m0 = blockIdx.x * 128 + wave * 32;   // NE divisible by 128, no guards
    const int lr = lane & 15;
    const int kg = lane >> 4;

    int e0 = m0 + lr, e1 = m0 + 16 + lr;
    int su0 = u[e0], sv0 = v[e0];
    int su1 = u[e1], sv1 = v[e1];

    f32x4 acc[2][8];
#pragma unroll
    for (int i = 0; i < 2; ++i)
#pragma unroll
        for (int j = 0; j < 8; ++j) acc[i][j] = (f32x4){0.f, 0.f, 0.f, 0.f};

    const __bf16* pw = W + (size_t)lr * 256 + 8 * kg;

#pragma unroll
    for (int half = 0; half < 2; ++half) {
        int n0 = half ? sv0 : su0;
        int n1 = half ? sv1 : su1;
        const __bf16* pa0 = H + (size_t)n0 * 128 + 8 * kg;
        const __bf16* pa1 = H + (size_t)n1 * 128 + 8 * kg;
#pragma unroll
        for (int kq = 0; kq < 128; kq += 32) {
            int k0 = half * 128 + kq;
            bf16x8 a0 = *(const bf16x8*)(pa0 + kq);
            bf16x8 a1 = *(const bf16x8*)(pa1 + kq);
#pragma unroll
            for (int j = 0; j < 8; ++j) {
                bf16x8 b = *(const bf16x8*)(pw + (size_t)j * 16 * 256 + k0);
                acc[0][j] = __builtin_amdgcn_mfma_f32_16x16x32_bf16(a0, b, acc[0][j], 0, 0, 0);
                acc[1][j] = __builtin_amdgcn_mfma_f32_16x16x32_bf16(a1, b, acc[1][j], 0, 0, 0);
            }
        }
    }

#pragma unroll
    for (int j = 0; j < 8; ++j) {
        int col = j * 16 + lr;
        float bb = bias[col];
#pragma unroll
        for (int i = 0; i < 2; ++i) {
#pragma unroll
            for (int r = 0; r < 4; ++r) {
                int row = m0 + i * 16 + kg * 4 + r;
                float val = fmaxf(acc[i][j][r] + bb, 0.f);
                if (SF32) Yf[(size_t)row * 128 + col] = val;
                else      Ybf[(size_t)row * 128 + col] = (__bf16)val;
            }
        }
    }
}

extern "C" void kernel_launch(void* const* d_in, const int* in_sizes, int n_in,
                              void* d_out, int out_size, void* d_ws, size_t ws_size,
                              hipStream_t stream) {
    const float* nfeats = (const float*)d_in[0];
    const float* efeats = (const float*)d_in[1];
    const int*   u      = (const int*)d_in[2];
    const int*   v      = (const int*)d_in[3];
    const float* W1a = (const float*)d_in[4];
    const float* b1a = (const float*)d_in[5];
    const float* W1e = (const float*)d_in[6];
    const float* b1e = (const float*)d_in[7];
    const float* W2a = (const float*)d_in[8];
    const float* b2a = (const float*)d_in[9];
    const float* W2e = (const float*)d_in[10];
    const float* b2e = (const float*)d_in[11];

    float* h2f = (float*)d_out;                       // [NN,128] f32 (output 0)
    float* e2f = h2f + (size_t)NN * 128;              // [NE,128] f32 (output 1)

    // e2 region (409.6 MB) is dead until the last kernel -> use as scratch
    char* eb = (char*)e2f;
    __bf16* e1bf = (__bf16*)(eb);                     // [NE,128]  204,800,000 B
    __bf16* Xbuf = (__bf16*)(eb + 204800000);         // [NN,384]   38,400,000 B
    __bf16* h1bf = (__bf16*)(eb + 243200000);         // [NN,128]   12,800,000 B

    char* w = (char*)d_ws;
    int* cnt = (int*)(w);                  // 200,000 B
    int* off = (int*)(w + 200000);         // 200,004 B
    int* cur = (int*)(w + 400016);         // 200,000 B
    int* eid = (int*)(w + 600016);         // 3,200,000 B
    __bf16* w1a  = (__bf16*)(w + 3800016); // 98,304 B
    __bf16* w1e  = (__bf16*)(w + 3898320); // 65,536 B
    __bf16* w2a  = (__bf16*)(w + 3963856); // 98,304 B
    __bf16* w2e  = (__bf16*)(w + 4062160); // 65,536 B
    __bf16* h2bf = (__bf16*)(w + 4127696); // 12,800,000 B  (total ~16.9 MB)

    // CSR build (reused by both layers)
    hipMemsetAsync(cnt, 0, NN * sizeof(int), stream);
    k_count<<<1024, 256, 0, stream>>>(v, cnt);
    k_scan<<<1, 1024, 0, stream>>>(cnt, off, cur);
    k_fill<<<1024, 256, 0, stream>>>(v, cur, eid);

    // weights -> bf16
    k_cvt<<<96, 256, 0, stream>>>(W1a, w1a, 128 * 384);
    k_cvt<<<64, 256, 0, stream>>>(W1e, w1e, 128 * 256);
    k_cvt<<<96, 256, 0, stream>>>(W2a, w2a, 128 * 384);
    k_cvt<<<64, 256, 0, stream>>>(W2e, w2e, 128 * 256);

    // layer 1
    k_agg<float, float><<<NN, 256, 0, stream>>>(nfeats, efeats, u, eid, off, Xbuf);
    k_mlp_node<384, false, true><<<(NN + 127) / 128, 256, 0, stream>>>(Xbuf, w1a, b1a, h1bf, nullptr, NN);
    k_mlp_edge<false><<<NE / 128, 256, 0, stream>>>(h1bf, u, v, w1e, b1e, e1bf, nullptr);

    // layer 2
    k_agg<__bf16, __bf16><<<NN, 256, 0, stream>>>(h1bf, e1bf, u, eid, off, Xbuf);
    k_mlp_node<384, true, true><<<(NN + 127) / 128, 256, 0, stream>>>(Xbuf, w2a, b2a, h2bf, h2f, NN);
    k_mlp_edge<true><<<NE / 128, 256, 0, stream>>>(h2bf, u, v, w2e, b2e, nullptr, e2f);
}

// Round 2
// 1109.393 us; speedup vs baseline: 1.3138x; 1.3138x over previous
//
#include <hip/hip_runtime.h>
#include <hip/hip_bf16.h>
#include <stdint.h>
#include <stddef.h>

#define NN 50000
#define NE 800000

typedef __attribute__((ext_vector_type(8))) __bf16 bf16x8;
typedef __attribute__((ext_vector_type(4))) __bf16 bf16x4;
typedef __attribute__((ext_vector_type(2))) __bf16 bf16x2;
typedef __attribute__((ext_vector_type(4))) float  f32x4;

static __device__ __forceinline__ float ldf(const float* p)  { return *p; }
static __device__ __forceinline__ float ldf(const __bf16* p) { return (float)(*p); }
static __device__ __forceinline__ f32x4 ld4(const float* p)  { return *(const f32x4*)p; }
static __device__ __forceinline__ f32x4 ld4(const __bf16* p) {
    bf16x4 v = *(const bf16x4*)p;
    return (f32x4){(float)v[0], (float)v[1], (float)v[2], (float)v[3]};
}

// ---------------- CSR build ----------------
__global__ __launch_bounds__(256) void k_count(const int* __restrict__ v, int* __restrict__ cnt) {
    int i = blockIdx.x * 256 + threadIdx.x;
    int stride = gridDim.x * 256;
    for (; i < NE; i += stride) atomicAdd(&cnt[v[i]], 1);
}

__global__ __launch_bounds__(1024) void k_scan(const int* __restrict__ cnt,
                                               int* __restrict__ off,
                                               int* __restrict__ cur) {
    __shared__ int sh[1024];
    const int T = 1024;
    const int C = (NN + T - 1) / T;   // 49
    int t = threadIdx.x;
    int base = t * C;
    int s = 0;
    for (int j = 0; j < C; ++j) {
        int idx = base + j;
        if (idx < NN) s += cnt[idx];
    }
    sh[t] = s;
    __syncthreads();
    for (int d = 1; d < T; d <<= 1) {
        int val = (t >= d) ? sh[t - d] : 0;
        __syncthreads();
        sh[t] += val;
        __syncthreads();
    }
    int run = sh[t] - s;   // exclusive prefix of this thread's chunk
    for (int j = 0; j < C; ++j) {
        int idx = base + j;
        if (idx < NN) {
            off[idx] = run; cur[idx] = run;
            run += cnt[idx];
        }
    }
    if (t == T - 1) off[NN] = sh[T - 1];
}

// fill CSR payload: se[pos] = {src_node, edge_id}
__global__ __launch_bounds__(256) void k_fill(const int* __restrict__ u,
                                              const int* __restrict__ v,
                                              int* __restrict__ cur,
                                              int2* __restrict__ se) {
    int i = blockIdx.x * 256 + threadIdx.x;
    int stride = gridDim.x * 256;
    for (; i < NE; i += stride) {
        int pos = atomicAdd(&cur[v[i]], 1);
        se[pos] = make_int2(u[i], i);
    }
}

// ---------------- all four weight matrices f32 -> bf16, one launch ----------------
__global__ __launch_bounds__(256) void k_cvtw(const float* __restrict__ a, __bf16* __restrict__ oa,
                                              const float* __restrict__ b, __bf16* __restrict__ ob,
                                              const float* __restrict__ c, __bf16* __restrict__ oc,
                                              const float* __restrict__ d, __bf16* __restrict__ od) {
    int i = blockIdx.x * 256 + threadIdx.x;
    int stride = gridDim.x * 256;
    for (; i < 128 * 384; i += stride) {
        oa[i] = (__bf16)a[i];
        oc[i] = (__bf16)c[i];
        if (i < 128 * 256) { ob[i] = (__bf16)b[i]; od[i] = (__bf16)d[i]; }
    }
}

// ---------------- mean aggregation + concat; writes X[n][384] bf16 ----------------
// one wave per node: lanes 0-31 gather src-node rows, lanes 32-63 gather edge rows,
// 16B (f32) / 8B (bf16) per lane, 4 edges in flight.
template <typename T>
__global__ __launch_bounds__(256) void k_agg(const T* __restrict__ nf,
                                             const T* __restrict__ ef,
                                             const int2* __restrict__ se,
                                             const int* __restrict__ off,
                                             __bf16* __restrict__ X) {
    const int wid  = threadIdx.x >> 6;
    const int lane = threadIdx.x & 63;
    const int n = blockIdx.x * 4 + wid;               // grid = NN/4 exactly
    const int p0 = __builtin_amdgcn_readfirstlane(off[n]);
    const int p1 = __builtin_amdgcn_readfirstlane(off[n + 1]);
    const bool isE = lane >= 32;
    const int l = lane & 31;
    const T* base = isE ? ef : nf;

    f32x4 acc = {0.f, 0.f, 0.f, 0.f};
    int p = p0;
    for (; p + 4 <= p1; p += 4) {
        int2 g0 = se[p], g1 = se[p + 1], g2 = se[p + 2], g3 = se[p + 3];
        f32x4 t0 = ld4(base + (size_t)(isE ? g0.y : g0.x) * 128 + l * 4);
        f32x4 t1 = ld4(base + (size_t)(isE ? g1.y : g1.x) * 128 + l * 4);
        f32x4 t2 = ld4(base + (size_t)(isE ? g2.y : g2.x) * 128 + l * 4);
        f32x4 t3 = ld4(base + (size_t)(isE ? g3.y : g3.x) * 128 + l * 4);
        acc += t0; acc += t1; acc += t2; acc += t3;
    }
    for (; p < p1; ++p) {
        int2 g = se[p];
        acc += ld4(base + (size_t)(isE ? g.y : g.x) * 128 + l * 4);
    }

    float inv = (p1 > p0) ? 1.f / (float)(p1 - p0) : 0.f;
    bf16x4 o;
    o[0] = (__bf16)(acc[0] * inv); o[1] = (__bf16)(acc[1] * inv);
    o[2] = (__bf16)(acc[2] * inv); o[3] = (__bf16)(acc[3] * inv);
    *(bf16x4*)(X + (size_t)n * 384 + 128 + (isE ? 128 : 0) + l * 4) = o;

    // self features -> X[:, 0:128]
    float s0 = ldf(nf + (size_t)n * 128 + lane * 2);
    float s1 = ldf(nf + (size_t)n * 128 + lane * 2 + 1);
    bf16x2 sc; sc[0] = (__bf16)s0; sc[1] = (__bf16)s1;
    *(bf16x2*)(X + (size_t)n * 384 + lane * 2) = sc;
}

// ---------------- node MLP: Y = relu(X[M,K] @ W[128,K]^T + b) ----------------
template <int K, bool SF32, bool SBF>
__global__ __launch_bounds__(256) void k_mlp_node(const __bf16* __restrict__ A,
                                                  const __bf16* __restrict__ W,
                                                  const float* __restrict__ bias,
                                                  __bf16* __restrict__ Ybf,
                                                  float* __restrict__ Yf,
                                                  int M) {
    const int wave = threadIdx.x >> 6;
    const int lane = threadIdx.x & 63;
    const int m0 = blockIdx.x * 128 + wave * 32;
    const int lr = lane & 15;
    const int kg = lane >> 4;

    f32x4 acc[2][8];
#pragma unroll
    for (int i = 0; i < 2; ++i)
#pragma unroll
        for (int j = 0; j < 8; ++j) acc[i][j] = (f32x4){0.f, 0.f, 0.f, 0.f};

    int ra0 = m0 + lr;      if (ra0 > M - 1) ra0 = M - 1;
    int ra1 = m0 + 16 + lr; if (ra1 > M - 1) ra1 = M - 1;
    const __bf16* pa0 = A + (size_t)ra0 * K + 8 * kg;
    const __bf16* pa1 = A + (size_t)ra1 * K + 8 * kg;
    const __bf16* pw  = W + (size_t)lr * K + 8 * kg;

#pragma unroll 4
    for (int k0 = 0; k0 < K; k0 += 32) {
        bf16x8 a0 = *(const bf16x8*)(pa0 + k0);
        bf16x8 a1 = *(const bf16x8*)(pa1 + k0);
#pragma unroll
        for (int j = 0; j < 8; ++j) {
            bf16x8 b = *(const bf16x8*)(pw + (size_t)j * 16 * K + k0);
            acc[0][j] = __builtin_amdgcn_mfma_f32_16x16x32_bf16(a0, b, acc[0][j], 0, 0, 0);
            acc[1][j] = __builtin_amdgcn_mfma_f32_16x16x32_bf16(a1, b, acc[1][j], 0, 0, 0);
        }
    }

#pragma unroll
    for (int j = 0; j < 8; ++j) {
        int col = j * 16 + lr;
        float bb = bias[col];
#pragma unroll
        for (int i = 0; i < 2; ++i) {
#pragma unroll
            for (int r = 0; r < 4; ++r) {
                int row = m0 + i * 16 + kg * 4 + r;
                if (row < M) {
                    float val = fmaxf(acc[i][j][r] + bb, 0.f);
                    if (SBF)  Ybf[(size_t)row * 128 + col] = (__bf16)val;
                    if (SF32) Yf[(size_t)row * 128 + col]  = val;
                }
            }
        }
    }
}

// ---------------- edge MLP: Y[e] = relu([H[u[e]],H[v[e]]] @ W[128,256]^T + b) ----------------
template <bool SF32>
__global__ __launch_bounds__(256) void k_mlp_edge(const __bf16* __restrict__ H,
                                                  const int* __restrict__ u,
                                                  const int* __restrict__ v,
                                                  const __bf16* __restrict__ W,
                                                  const float* __restrict__ bias,
                                                  __bf16* __restrict__ Ybf,
                                                  float* __restrict__ Yf) {
    const int wave = threadIdx.x >> 6;
    const int lane = threadIdx.x & 63;
    const int m0 = blockIdx.x * 128 + wave * 32;   // NE divisible by 128, no guards
    const int lr = lane & 15;
    const int kg = lane >> 4;

    int e0 = m0 + lr, e1 = m0 + 16 + lr;
    int su0 = u[e0], sv0 = v[e0];
    int su1 = u[e1], sv1 = v[e1];

    f32x4 acc[2][8];
#pragma unroll
    for (int i = 0; i < 2; ++i)
#pragma unroll
        for (int j = 0; j < 8; ++j) acc[i][j] = (f32x4){0.f, 0.f, 0.f, 0.f};

    const __bf16* pw = W + (size_t)lr * 256 + 8 * kg;

#pragma unroll
    for (int half = 0; half < 2; ++half) {
        int n0 = half ? sv0 : su0;
        int n1 = half ? sv1 : su1;
        const __bf16* pa0 = H + (size_t)n0 * 128 + 8 * kg;
        const __bf16* pa1 = H + (size_t)n1 * 128 + 8 * kg;
#pragma unroll
        for (int kq = 0; kq < 128; kq += 32) {
            int k0 = half * 128 + kq;
            bf16x8 a0 = *(const bf16x8*)(pa0 + kq);
            bf16x8 a1 = *(const bf16x8*)(pa1 + kq);
#pragma unroll
            for (int j = 0; j < 8; ++j) {
                bf16x8 b = *(const bf16x8*)(pw + (size_t)j * 16 * 256 + k0);
                acc[0][j] = __builtin_amdgcn_mfma_f32_16x16x32_bf16(a0, b, acc[0][j], 0, 0, 0);
                acc[1][j] = __builtin_amdgcn_mfma_f32_16x16x32_bf16(a1, b, acc[1][j], 0, 0, 0);
            }
        }
    }

#pragma unroll
    for (int j = 0; j < 8; ++j) {
        int col = j * 16 + lr;
        float bb = bias[col];
#pragma unroll
        for (int i = 0; i < 2; ++i) {
#pragma unroll
            for (int r = 0; r < 4; ++r) {
                int row = m0 + i * 16 + kg * 4 + r;
                float val = fmaxf(acc[i][j][r] + bb, 0.f);
                if (SF32) Yf[(size_t)row * 128 + col] = val;
                else      Ybf[(size_t)row * 128 + col] = (__bf16)val;
            }
        }
    }
}

extern "C" void kernel_launch(void* const* d_in, const int* in_sizes, int n_in,
                              void* d_out, int out_size, void* d_ws, size_t ws_size,
                              hipStream_t stream) {
    const float* nfeats = (const float*)d_in[0];
    const float* efeats = (const float*)d_in[1];
    const int*   u      = (const int*)d_in[2];
    const int*   v      = (const int*)d_in[3];
    const float* W1a = (const float*)d_in[4];
    const float* b1a = (const float*)d_in[5];
    const float* W1e = (const float*)d_in[6];
    const float* b1e = (const float*)d_in[7];
    const float* W2a = (const float*)d_in[8];
    const float* b2a = (const float*)d_in[9];
    const float* W2e = (const float*)d_in[10];
    const float* b2e = (const float*)d_in[11];

    float* h2f = (float*)d_out;                       // [NN,128] f32 (output 0)
    float* e2f = h2f + (size_t)NN * 128;              // [NE,128] f32 (output 1)

    // e2 region (409.6 MB) is dead until the last kernel -> use as scratch
    char* eb = (char*)e2f;
    __bf16* e1bf = (__bf16*)(eb);                     // [NE,128]  204,800,000 B
    __bf16* Xbuf = (__bf16*)(eb + 204800000);         // [NN,384]   38,400,000 B
    __bf16* h1bf = (__bf16*)(eb + 243200000);         // [NN,128]   12,800,000 B
    int2*   se   = (int2*)  (eb + 256000000);         // [NE]        6,400,000 B

    char* w = (char*)d_ws;
    int* cnt = (int*)(w);                   // 200,000 B
    int* off = (int*)(w + 200000);          // 200,004 B (padded)
    int* cur = (int*)(w + 400016);          // 200,000 B
    __bf16* w1a  = (__bf16*)(w + 600016);   // 98,304 B
    __bf16* w1e  = (__bf16*)(w + 698320);   // 65,536 B
    __bf16* w2a  = (__bf16*)(w + 763856);   // 98,304 B
    __bf16* w2e  = (__bf16*)(w + 862160);   // 65,536 B
    __bf16* h2bf = (__bf16*)(w + 927696);   // 12,800,000 B  (total ~13.7 MB)

    // CSR build (reused by both layers)
    hipMemsetAsync(cnt, 0, NN * sizeof(int), stream);
    k_count<<<1024, 256, 0, stream>>>(v, cnt);
    k_scan<<<1, 1024, 0, stream>>>(cnt, off, cur);
    k_fill<<<1024, 256, 0, stream>>>(u, v, cur, se);

    // weights -> bf16 (single launch)
    k_cvtw<<<192, 256, 0, stream>>>(W1a, w1a, W1e, w1e, W2a, w2a, W2e, w2e);

    // layer 1
    k_agg<float><<<NN / 4, 256, 0, stream>>>(nfeats, efeats, se, off, Xbuf);
    k_mlp_node<384, false, true><<<(NN + 127) / 128, 256, 0, stream>>>(Xbuf, w1a, b1a, h1bf, nullptr, NN);
    k_mlp_edge<false><<<NE / 128, 256, 0, stream>>>(h1bf, u, v, w1e, b1e, e1bf, nullptr);

    // layer 2
    k_agg<__bf16><<<NN / 4, 256, 0, stream>>>(h1bf, e1bf, se, off, Xbuf);
    k_mlp_node<384, true, true><<<(NN + 127) / 128, 256, 0, stream>>>(Xbuf, w2a, b2a, h2bf, h2f, NN);
    k_mlp_edge<true><<<NE / 128, 256, 0, stream>>>(h2bf, u, v, w2e, b2e, nullptr, e2f);
}

// Round 3
// 837.447 us; speedup vs baseline: 1.7405x; 1.3247x over previous
//
#include <hip/hip_runtime.h>
#include <hip/hip_bf16.h>
#include <stdint.h>
#include <stddef.h>

#define NN 50000
#define NE 800000

typedef __attribute__((ext_vector_type(8))) __bf16 bf16x8;
typedef __attribute__((ext_vector_type(4))) __bf16 bf16x4;
typedef __attribute__((ext_vector_type(2))) __bf16 bf16x2;
typedef __attribute__((ext_vector_type(4))) float  f32x4;

static __device__ __forceinline__ f32x4 ld4(const float* p)  { return *(const f32x4*)p; }
static __device__ __forceinline__ f32x4 ld4(const __bf16* p) {
    bf16x4 v = *(const bf16x4*)p;
    return (f32x4){(float)v[0], (float)v[1], (float)v[2], (float)v[3]};
}
static __device__ __forceinline__ bf16x8 ld8b(const __bf16* p) { return *(const bf16x8*)p; }
static __device__ __forceinline__ bf16x8 ld8b(const float* p) {
    f32x4 a = *(const f32x4*)p, b = *(const f32x4*)(p + 4);
    bf16x8 r;
    r[0] = (__bf16)a[0]; r[1] = (__bf16)a[1]; r[2] = (__bf16)a[2]; r[3] = (__bf16)a[3];
    r[4] = (__bf16)b[0]; r[5] = (__bf16)b[1]; r[6] = (__bf16)b[2]; r[7] = (__bf16)b[3];
    return r;
}
static __device__ __forceinline__ f32x4 relu4(f32x4 a) {
    return (f32x4){fmaxf(a[0], 0.f), fmaxf(a[1], 0.f), fmaxf(a[2], 0.f), fmaxf(a[3], 0.f)};
}

// ---------------- CSR build ----------------
__global__ __launch_bounds__(256) void k_count(const int* __restrict__ v, int* __restrict__ cnt) {
    int i = blockIdx.x * 256 + threadIdx.x;
    int stride = gridDim.x * 256;
    for (; i < NE; i += stride) atomicAdd(&cnt[v[i]], 1);
}

__global__ __launch_bounds__(1024) void k_scan(const int* __restrict__ cnt,
                                               int* __restrict__ off,
                                               int* __restrict__ cur) {
    __shared__ int sh[1024];
    const int T = 1024;
    const int C = (NN + T - 1) / T;
    int t = threadIdx.x;
    int base = t * C;
    int s = 0;
    for (int j = 0; j < C; ++j) {
        int idx = base + j;
        if (idx < NN) s += cnt[idx];
    }
    sh[t] = s;
    __syncthreads();
    for (int d = 1; d < T; d <<= 1) {
        int val = (t >= d) ? sh[t - d] : 0;
        __syncthreads();
        sh[t] += val;
        __syncthreads();
    }
    int run = sh[t] - s;
    for (int j = 0; j < C; ++j) {
        int idx = base + j;
        if (idx < NN) {
            off[idx] = run; cur[idx] = run;
            run += cnt[idx];
        }
    }
    if (t == T - 1) off[NN] = sh[T - 1];
}

__global__ __launch_bounds__(256) void k_fill(const int* __restrict__ u,
                                              const int* __restrict__ v,
                                              int* __restrict__ cur,
                                              int2* __restrict__ se) {
    int i = blockIdx.x * 256 + threadIdx.x;
    int stride = gridDim.x * 256;
    for (; i < NE; i += stride) {
        int pos = atomicAdd(&cur[v[i]], 1);
        se[pos] = make_int2(u[i], i);
    }
}

// ---------------- all four weight matrices f32 -> bf16, one launch ----------------
__global__ __launch_bounds__(256) void k_cvtw(const float* __restrict__ a, __bf16* __restrict__ oa,
                                              const float* __restrict__ b, __bf16* __restrict__ ob,
                                              const float* __restrict__ c, __bf16* __restrict__ oc,
                                              const float* __restrict__ d, __bf16* __restrict__ od) {
    int i = blockIdx.x * 256 + threadIdx.x;
    int stride = gridDim.x * 256;
    for (; i < 128 * 384; i += stride) {
        oa[i] = (__bf16)a[i];
        oc[i] = (__bf16)c[i];
        if (i < 128 * 256) { ob[i] = (__bf16)b[i]; od[i] = (__bf16)d[i]; }
    }
}

// ---------------- layer-1 aggregation: X1 = [nf, mean nf[u], mean ef] ----------------
__global__ __launch_bounds__(256) void k_agg1(const float* __restrict__ nf,
                                              const float* __restrict__ ef,
                                              const int2* __restrict__ se,
                                              const int* __restrict__ off,
                                              __bf16* __restrict__ X) {
    const int wid  = threadIdx.x >> 6;
    const int lane = threadIdx.x & 63;
    const int n = blockIdx.x * 4 + wid;
    const int p0 = __builtin_amdgcn_readfirstlane(off[n]);
    const int p1 = __builtin_amdgcn_readfirstlane(off[n + 1]);
    const bool isE = lane >= 32;
    const int l = lane & 31;
    const float* base = isE ? ef : nf;

    f32x4 acc = {0.f, 0.f, 0.f, 0.f};
    int p = p0;
    for (; p + 4 <= p1; p += 4) {
        int2 g0 = se[p], g1 = se[p + 1], g2 = se[p + 2], g3 = se[p + 3];
        f32x4 t0 = ld4(base + (size_t)(isE ? g0.y : g0.x) * 128 + l * 4);
        f32x4 t1 = ld4(base + (size_t)(isE ? g1.y : g1.x) * 128 + l * 4);
        f32x4 t2 = ld4(base + (size_t)(isE ? g2.y : g2.x) * 128 + l * 4);
        f32x4 t3 = ld4(base + (size_t)(isE ? g3.y : g3.x) * 128 + l * 4);
        acc += t0; acc += t1; acc += t2; acc += t3;
    }
    for (; p < p1; ++p) {
        int2 g = se[p];
        acc += ld4(base + (size_t)(isE ? g.y : g.x) * 128 + l * 4);
    }

    float inv = (p1 > p0) ? 1.f / (float)(p1 - p0) : 0.f;
    bf16x4 o;
    o[0] = (__bf16)(acc[0] * inv); o[1] = (__bf16)(acc[1] * inv);
    o[2] = (__bf16)(acc[2] * inv); o[3] = (__bf16)(acc[3] * inv);
    *(bf16x4*)(X + (size_t)n * 384 + 128 + (isE ? 128 : 0) + l * 4) = o;

    // self features -> X[:, 0:128]
    float s0 = nf[(size_t)n * 128 + lane * 2];
    float s1 = nf[(size_t)n * 128 + lane * 2 + 1];
    bf16x2 sc; sc[0] = (__bf16)s0; sc[1] = (__bf16)s1;
    *(bf16x2*)(X + (size_t)n * 384 + lane * 2) = sc;
}

// ---------------- layer-2 aggregation with fused edge-MLP ----------------
// X2[n] = [h1[n], mean h1[u[e]], mean relu(P1[u[e]] + Q1[n] + b1e)]
__global__ __launch_bounds__(256) void k_agg2(const float* __restrict__ h1,
                                              const float* __restrict__ P1,
                                              const float* __restrict__ Q1,
                                              const float* __restrict__ b1e,
                                              const int2* __restrict__ se,
                                              const int* __restrict__ off,
                                              __bf16* __restrict__ X) {
    const int wid  = threadIdx.x >> 6;
    const int lane = threadIdx.x & 63;
    const int n = blockIdx.x * 4 + wid;
    const int p0 = __builtin_amdgcn_readfirstlane(off[n]);
    const int p1 = __builtin_amdgcn_readfirstlane(off[n + 1]);
    const bool isE = lane >= 32;
    const int l = lane & 31;
    const float* base = isE ? P1 : h1;

    // wave-uniform per node: qb = Q1[n] + b1e (only used by edge lanes)
    f32x4 qb = ld4(Q1 + (size_t)n * 128 + l * 4) + ld4(b1e + l * 4);

    f32x4 acc = {0.f, 0.f, 0.f, 0.f};
    int p = p0;
    for (; p + 4 <= p1; p += 4) {
        int2 g0 = se[p], g1 = se[p + 1], g2 = se[p + 2], g3 = se[p + 3];
        f32x4 t0 = ld4(base + (size_t)g0.x * 128 + l * 4);
        f32x4 t1 = ld4(base + (size_t)g1.x * 128 + l * 4);
        f32x4 t2 = ld4(base + (size_t)g2.x * 128 + l * 4);
        f32x4 t3 = ld4(base + (size_t)g3.x * 128 + l * 4);
        if (isE) { t0 = relu4(t0 + qb); t1 = relu4(t1 + qb); t2 = relu4(t2 + qb); t3 = relu4(t3 + qb); }
        acc += t0; acc += t1; acc += t2; acc += t3;
    }
    for (; p < p1; ++p) {
        int2 g = se[p];
        f32x4 t = ld4(base + (size_t)g.x * 128 + l * 4);
        if (isE) t = relu4(t + qb);
        acc += t;
    }

    float inv = (p1 > p0) ? 1.f / (float)(p1 - p0) : 0.f;
    bf16x4 o;
    o[0] = (__bf16)(acc[0] * inv); o[1] = (__bf16)(acc[1] * inv);
    o[2] = (__bf16)(acc[2] * inv); o[3] = (__bf16)(acc[3] * inv);
    *(bf16x4*)(X + (size_t)n * 384 + 128 + (isE ? 128 : 0) + l * 4) = o;

    // self features h1[n] -> X[:, 0:128]
    float s0 = h1[(size_t)n * 128 + lane * 2];
    float s1 = h1[(size_t)n * 128 + lane * 2 + 1];
    bf16x2 sc; sc[0] = (__bf16)s0; sc[1] = (__bf16)s1;
    *(bf16x2*)(X + (size_t)n * 384 + lane * 2) = sc;
}

// ---------------- node MLP: Y = relu(X[M,K] @ W[128,K]^T + b) ----------------
// swapped operands: A = weight rows (m=channel), B = X rows (n=node)
// -> each lane stores contiguous f32x4 / bf16x4 (coalesced).
template <int K, bool SF32, bool SBF>
__global__ __launch_bounds__(256) void k_mlp_node(const __bf16* __restrict__ A,
                                                  const __bf16* __restrict__ W,
                                                  const float* __restrict__ bias,
                                                  __bf16* __restrict__ Ybf,
                                                  float* __restrict__ Yf,
                                                  int M) {
    const int wave = threadIdx.x >> 6;
    const int lane = threadIdx.x & 63;
    const int m0 = blockIdx.x * 128 + wave * 32;
    const int lr = lane & 15;
    const int kg = lane >> 4;

    f32x4 acc[2][8];
#pragma unroll
    for (int i = 0; i < 2; ++i)
#pragma unroll
        for (int j = 0; j < 8; ++j) acc[i][j] = (f32x4){0.f, 0.f, 0.f, 0.f};

    int r0 = m0 + lr;      if (r0 > M - 1) r0 = M - 1;
    int r1 = m0 + 16 + lr; if (r1 > M - 1) r1 = M - 1;
    const __bf16* px0 = A + (size_t)r0 * K + 8 * kg;
    const __bf16* px1 = A + (size_t)r1 * K + 8 * kg;
    const __bf16* pw  = W + (size_t)lr * K + 8 * kg;

#pragma unroll 4
    for (int k0 = 0; k0 < K; k0 += 32) {
        bf16x8 x0 = *(const bf16x8*)(px0 + k0);
        bf16x8 x1 = *(const bf16x8*)(px1 + k0);
#pragma unroll
        for (int j = 0; j < 8; ++j) {
            bf16x8 w = *(const bf16x8*)(pw + (size_t)j * 16 * K + k0);
            acc[0][j] = __builtin_amdgcn_mfma_f32_16x16x32_bf16(w, x0, acc[0][j], 0, 0, 0);
            acc[1][j] = __builtin_amdgcn_mfma_f32_16x16x32_bf16(w, x1, acc[1][j], 0, 0, 0);
        }
    }

#pragma unroll
    for (int i = 0; i < 2; ++i) {
        int node = m0 + i * 16 + lr;
        if (node >= M) continue;
#pragma unroll
        for (int j = 0; j < 8; ++j) {
            int ch0 = j * 16 + kg * 4;
            f32x4 bb = *(const f32x4*)(bias + ch0);
            f32x4 val = relu4(acc[i][j] + bb);
            if (SF32) *(f32x4*)(Yf + (size_t)node * 128 + ch0) = val;
            if (SBF) {
                bf16x4 ob;
                ob[0] = (__bf16)val[0]; ob[1] = (__bf16)val[1];
                ob[2] = (__bf16)val[2]; ob[3] = (__bf16)val[3];
                *(bf16x4*)(Ybf + (size_t)node * 128 + ch0) = ob;
            }
        }
    }
}

// ---------------- P/Q: P = H @ We[:, :128]^T,  Q = H @ We[:, 128:]^T ----------------
template <typename TI, typename TO>
__global__ __launch_bounds__(256) void k_pq(const TI* __restrict__ H,
                                            const __bf16* __restrict__ We, /* [128,256] */
                                            TO* __restrict__ P,
                                            TO* __restrict__ Q) {
    const int wave = threadIdx.x >> 6;
    const int lane = threadIdx.x & 63;
    const int n0 = blockIdx.x * 64 + wave * 16;
    const int lr = lane & 15;
    const int kg = lane >> 4;

    f32x4 accP[8], accQ[8];
#pragma unroll
    for (int j = 0; j < 8; ++j) { accP[j] = (f32x4){0,0,0,0}; accQ[j] = (f32x4){0,0,0,0}; }

    int row = n0 + lr; if (row > NN - 1) row = NN - 1;
    const TI* ph = H + (size_t)row * 128 + 8 * kg;
    const __bf16* pw = We + (size_t)lr * 256 + 8 * kg;

#pragma unroll
    for (int k0 = 0; k0 < 128; k0 += 32) {
        bf16x8 h = ld8b(ph + k0);
#pragma unroll
        for (int j = 0; j < 8; ++j) {
            bf16x8 wp = *(const bf16x8*)(pw + (size_t)j * 16 * 256 + k0);
            bf16x8 wq = *(const bf16x8*)(pw + (size_t)j * 16 * 256 + 128 + k0);
            accP[j] = __builtin_amdgcn_mfma_f32_16x16x32_bf16(wp, h, accP[j], 0, 0, 0);
            accQ[j] = __builtin_amdgcn_mfma_f32_16x16x32_bf16(wq, h, accQ[j], 0, 0, 0);
        }
    }

    int node = n0 + lr;
    if (node < NN) {
#pragma unroll
        for (int j = 0; j < 8; ++j) {
            int ch0 = j * 16 + kg * 4;
            if (sizeof(TO) == 4) {
                *(f32x4*)((float*)P + (size_t)node * 128 + ch0) = accP[j];
                *(f32x4*)((float*)Q + (size_t)node * 128 + ch0) = accQ[j];
            } else {
                bf16x4 op, oq;
#pragma unroll
                for (int r = 0; r < 4; ++r) { op[r] = (__bf16)accP[j][r]; oq[r] = (__bf16)accQ[j][r]; }
                *(bf16x4*)((__bf16*)P + (size_t)node * 128 + ch0) = op;
                *(bf16x4*)((__bf16*)Q + (size_t)node * 128 + ch0) = oq;
            }
        }
    }
}

// ---------------- final edge op: e2 = relu(P2[u] + Q2[v] + b2e) ----------------
template <typename TP>
__global__ __launch_bounds__(256) void k_add2(const TP* __restrict__ P,
                                              const TP* __restrict__ Q,
                                              const int* __restrict__ u,
                                              const int* __restrict__ v,
                                              const float* __restrict__ bias,
                                              float* __restrict__ out) {
    const int l = threadIdx.x & 31;
    const int sub = threadIdx.x >> 5;           // 0..7
    const int e0 = blockIdx.x * 16 + sub * 2;   // 16 edges per block, 2 per thread
    f32x4 bb = *(const f32x4*)(bias + l * 4);

    int u0 = u[e0], v0 = v[e0], u1 = u[e0 + 1], v1 = v[e0 + 1];
    f32x4 p0 = ld4(P + (size_t)u0 * 128 + l * 4);
    f32x4 q0 = ld4(Q + (size_t)v0 * 128 + l * 4);
    f32x4 p1 = ld4(P + (size_t)u1 * 128 + l * 4);
    f32x4 q1 = ld4(Q + (size_t)v1 * 128 + l * 4);
    *(f32x4*)(out + (size_t)e0 * 128 + l * 4)       = relu4(p0 + q0 + bb);
    *(f32x4*)(out + (size_t)(e0 + 1) * 128 + l * 4) = relu4(p1 + q1 + bb);
}

extern "C" void kernel_launch(void* const* d_in, const int* in_sizes, int n_in,
                              void* d_out, int out_size, void* d_ws, size_t ws_size,
                              hipStream_t stream) {
    const float* nfeats = (const float*)d_in[0];
    const float* efeats = (const float*)d_in[1];
    const int*   u      = (const int*)d_in[2];
    const int*   v      = (const int*)d_in[3];
    const float* W1a = (const float*)d_in[4];
    const float* b1a = (const float*)d_in[5];
    const float* W1e = (const float*)d_in[6];
    const float* b1e = (const float*)d_in[7];
    const float* W2a = (const float*)d_in[8];
    const float* b2a = (const float*)d_in[9];
    const float* W2e = (const float*)d_in[10];
    const float* b2e = (const float*)d_in[11];

    float* h2f = (float*)d_out;                       // [NN,128] f32 (output 0)
    float* e2f = h2f + (size_t)NN * 128;              // [NE,128] f32 (output 1)

    // e2 region (409.6 MB) is scratch until k_add2 writes it
    char* eb = (char*)e2f;
    __bf16* Xbuf = (__bf16*)(eb);                     // [NN,384]  38,400,000 B
    float*  h1f  = (float*) (eb + 38400000);          // [NN,128]  25,600,000 B
    float*  P1   = (float*) (eb + 64000000);          // [NN,128]  25,600,000 B
    float*  Q1   = (float*) (eb + 89600000);          // [NN,128]  25,600,000 B
    int2*   se   = (int2*)  (eb + 115200000);         // [NE]       6,400,000 B

    char* w = (char*)d_ws;
    int* cnt = (int*)(w);                   // 200,000 B
    int* off = (int*)(w + 200000);          // 200,004 B (padded)
    int* cur = (int*)(w + 400016);          // 200,000 B
    __bf16* w1a  = (__bf16*)(w + 600016);   // 98,304 B
    __bf16* w1e  = (__bf16*)(w + 698320);   // 65,536 B
    __bf16* w2a  = (__bf16*)(w + 763856);   // 98,304 B
    __bf16* w2e  = (__bf16*)(w + 862160);   // 65,536 B
    char*   pqb  = w + 927696;              // P2/Q2 here (outside e2 region!)

    const size_t PQ_F32 = (size_t)NN * 128 * 4;   // 25,600,000
    const size_t PQ_BF  = (size_t)NN * 128 * 2;   // 12,800,000
    bool pq_f32 = ws_size >= 927696 + 2 * PQ_F32; // ~52.2 MB

    // CSR build
    hipMemsetAsync(cnt, 0, NN * sizeof(int), stream);
    k_count<<<1024, 256, 0, stream>>>(v, cnt);
    k_scan<<<1, 1024, 0, stream>>>(cnt, off, cur);
    k_fill<<<1024, 256, 0, stream>>>(u, v, cur, se);

    // weights -> bf16
    k_cvtw<<<192, 256, 0, stream>>>(W1a, w1a, W1e, w1e, W2a, w2a, W2e, w2e);

    // layer 1
    k_agg1<<<NN / 4, 256, 0, stream>>>(nfeats, efeats, se, off, Xbuf);
    k_mlp_node<384, true, false><<<(NN + 127) / 128, 256, 0, stream>>>(Xbuf, w1a, b1a, nullptr, h1f, NN);
    k_pq<float, float><<<(NN + 63) / 64, 256, 0, stream>>>(h1f, w1e, P1, Q1);

    // layer 2 (edge-MLP of layer 1 fused into aggregation)
    k_agg2<<<NN / 4, 256, 0, stream>>>(h1f, P1, Q1, b1e, se, off, Xbuf);
    k_mlp_node<384, true, false><<<(NN + 127) / 128, 256, 0, stream>>>(Xbuf, w2a, b2a, nullptr, h2f, NN);

    if (pq_f32) {
        float* P2 = (float*)pqb;
        float* Q2 = (float*)(pqb + PQ_F32);
        k_pq<float, float><<<(NN + 63) / 64, 256, 0, stream>>>(h2f, w2e, P2, Q2);
        k_add2<float><<<NE / 16, 256, 0, stream>>>(P2, Q2, u, v, b2e, e2f);
    } else {
        __bf16* P2 = (__bf16*)pqb;
        __bf16* Q2 = (__bf16*)(pqb + PQ_BF);
        k_pq<float, __bf16><<<(NN + 63) / 64, 256, 0, stream>>>(h2f, w2e, P2, Q2);
        k_add2<__bf16><<<NE / 16, 256, 0, stream>>>(P2, Q2, u, v, b2e, e2f);
    }
}

// Round 4
// 726.630 us; speedup vs baseline: 2.0059x; 1.1525x over previous
//
#include <hip/hip_runtime.h>
#include <hip/hip_bf16.h>
#include <stdint.h>
#include <stddef.h>

#define NN 50000
#define NE 800000

typedef __attribute__((ext_vector_type(8))) __bf16 bf16x8;
typedef __attribute__((ext_vector_type(4))) __bf16 bf16x4;
typedef __attribute__((ext_vector_type(2))) __bf16 bf16x2;
typedef __attribute__((ext_vector_type(4))) float  f32x4;

static __device__ __forceinline__ f32x4 ld4(const float* p)  { return *(const f32x4*)p; }
static __device__ __forceinline__ f32x4 ld4(const __bf16* p) {
    bf16x4 v = *(const bf16x4*)p;
    return (f32x4){(float)v[0], (float)v[1], (float)v[2], (float)v[3]};
}
static __device__ __forceinline__ bf16x8 ld8b(const __bf16* p) { return *(const bf16x8*)p; }
static __device__ __forceinline__ bf16x8 ld8b(const float* p) {
    f32x4 a = *(const f32x4*)p, b = *(const f32x4*)(p + 4);
    bf16x8 r;
    r[0] = (__bf16)a[0]; r[1] = (__bf16)a[1]; r[2] = (__bf16)a[2]; r[3] = (__bf16)a[3];
    r[4] = (__bf16)b[0]; r[5] = (__bf16)b[1]; r[6] = (__bf16)b[2]; r[7] = (__bf16)b[3];
    return r;
}
static __device__ __forceinline__ f32x4 relu4(f32x4 a) {
    return (f32x4){fmaxf(a[0], 0.f), fmaxf(a[1], 0.f), fmaxf(a[2], 0.f), fmaxf(a[3], 0.f)};
}
static __device__ __forceinline__ bf16x4 tobf4(f32x4 a) {
    bf16x4 o; o[0] = (__bf16)a[0]; o[1] = (__bf16)a[1]; o[2] = (__bf16)a[2]; o[3] = (__bf16)a[3];
    return o;
}

// ---------------- zero counters (hipMemsetAsync's fillBufferAligned took 255us!) ----------------
__global__ __launch_bounds__(256) void k_zero(int* __restrict__ cnt) {
    int i = blockIdx.x * 256 + threadIdx.x;
    if (i < NN) cnt[i] = 0;
}

// ---------------- CSR build ----------------
__global__ __launch_bounds__(256) void k_count(const int* __restrict__ v, int* __restrict__ cnt) {
    int i = blockIdx.x * 256 + threadIdx.x;
    int stride = gridDim.x * 256;
    for (; i < NE; i += stride) atomicAdd(&cnt[v[i]], 1);
}

__global__ __launch_bounds__(1024) void k_scan(const int* __restrict__ cnt,
                                               int* __restrict__ off,
                                               int* __restrict__ cur) {
    __shared__ int sh[1024];
    const int T = 1024;
    const int C = (NN + T - 1) / T;
    int t = threadIdx.x;
    int base = t * C;
    int s = 0;
    for (int j = 0; j < C; ++j) {
        int idx = base + j;
        if (idx < NN) s += cnt[idx];
    }
    sh[t] = s;
    __syncthreads();
    for (int d = 1; d < T; d <<= 1) {
        int val = (t >= d) ? sh[t - d] : 0;
        __syncthreads();
        sh[t] += val;
        __syncthreads();
    }
    int run = sh[t] - s;
    for (int j = 0; j < C; ++j) {
        int idx = base + j;
        if (idx < NN) {
            off[idx] = run; cur[idx] = run;
            run += cnt[idx];
        }
    }
    if (t == T - 1) off[NN] = sh[T - 1];
}

__global__ __launch_bounds__(256) void k_fill(const int* __restrict__ u,
                                              const int* __restrict__ v,
                                              int* __restrict__ cur,
                                              int2* __restrict__ se) {
    int i = blockIdx.x * 256 + threadIdx.x;
    int stride = gridDim.x * 256;
    for (; i < NE; i += stride) {
        int pos = atomicAdd(&cur[v[i]], 1);
        se[pos] = make_int2(u[i], i);
    }
}

// ---------------- all four weight matrices f32 -> bf16, one launch ----------------
__global__ __launch_bounds__(256) void k_cvtw(const float* __restrict__ a, __bf16* __restrict__ oa,
                                              const float* __restrict__ b, __bf16* __restrict__ ob,
                                              const float* __restrict__ c, __bf16* __restrict__ oc,
                                              const float* __restrict__ d, __bf16* __restrict__ od) {
    int i = blockIdx.x * 256 + threadIdx.x;
    int stride = gridDim.x * 256;
    for (; i < 128 * 384; i += stride) {
        oa[i] = (__bf16)a[i];
        oc[i] = (__bf16)c[i];
        if (i < 128 * 256) { ob[i] = (__bf16)b[i]; od[i] = (__bf16)d[i]; }
    }
}

// ---------------- layer-1 aggregation: X1 = [nf, mean nf[u], mean ef] ----------------
__global__ __launch_bounds__(256) void k_agg1(const float* __restrict__ nf,
                                              const float* __restrict__ ef,
                                              const int2* __restrict__ se,
                                              const int* __restrict__ off,
                                              __bf16* __restrict__ X) {
    const int wid  = threadIdx.x >> 6;
    const int lane = threadIdx.x & 63;
    const int n = blockIdx.x * 4 + wid;
    const int p0 = __builtin_amdgcn_readfirstlane(off[n]);
    const int p1 = __builtin_amdgcn_readfirstlane(off[n + 1]);
    const bool isE = lane >= 32;
    const int l = lane & 31;
    const float* base = isE ? ef : nf;

    f32x4 acc = {0.f, 0.f, 0.f, 0.f};
    int p = p0;
    for (; p + 8 <= p1; p += 8) {
        int2 g[8];
#pragma unroll
        for (int j = 0; j < 8; ++j) g[j] = se[p + j];
        f32x4 t[8];
#pragma unroll
        for (int j = 0; j < 8; ++j)
            t[j] = ld4(base + (size_t)(isE ? g[j].y : g[j].x) * 128 + l * 4);
#pragma unroll
        for (int j = 0; j < 8; ++j) acc += t[j];
    }
    for (; p < p1; ++p) {
        int2 g = se[p];
        acc += ld4(base + (size_t)(isE ? g.y : g.x) * 128 + l * 4);
    }

    float inv = (p1 > p0) ? 1.f / (float)(p1 - p0) : 0.f;
    f32x4 m = {acc[0] * inv, acc[1] * inv, acc[2] * inv, acc[3] * inv};
    *(bf16x4*)(X + (size_t)n * 384 + 128 + (isE ? 128 : 0) + l * 4) = tobf4(m);

    // self features -> X[:, 0:128]
    float s0 = nf[(size_t)n * 128 + lane * 2];
    float s1 = nf[(size_t)n * 128 + lane * 2 + 1];
    bf16x2 sc; sc[0] = (__bf16)s0; sc[1] = (__bf16)s1;
    *(bf16x2*)(X + (size_t)n * 384 + lane * 2) = sc;
}

// ---------------- layer-2 aggregation with fused edge-MLP (all gathers bf16) ----------------
// X2[n] = [h1[n], mean h1[u[e]], mean relu(P1[u[e]] + Q1[n] + b1e)]
__global__ __launch_bounds__(256) void k_agg2(const __bf16* __restrict__ h1,
                                              const __bf16* __restrict__ P1,
                                              const __bf16* __restrict__ Q1,
                                              const float* __restrict__ b1e,
                                              const int2* __restrict__ se,
                                              const int* __restrict__ off,
                                              __bf16* __restrict__ X) {
    const int wid  = threadIdx.x >> 6;
    const int lane = threadIdx.x & 63;
    const int n = blockIdx.x * 4 + wid;
    const int p0 = __builtin_amdgcn_readfirstlane(off[n]);
    const int p1 = __builtin_amdgcn_readfirstlane(off[n + 1]);
    const bool isE = lane >= 32;
    const int l = lane & 31;
    const __bf16* base = isE ? P1 : h1;

    // wave-uniform per node (only meaningful for edge lanes)
    f32x4 qb = ld4(Q1 + (size_t)n * 128 + l * 4) + ld4(b1e + l * 4);

    f32x4 acc = {0.f, 0.f, 0.f, 0.f};
    int p = p0;
    for (; p + 8 <= p1; p += 8) {
        int g[8];
#pragma unroll
        for (int j = 0; j < 8; ++j) g[j] = se[p + j].x;
        f32x4 t[8];
#pragma unroll
        for (int j = 0; j < 8; ++j) t[j] = ld4(base + (size_t)g[j] * 128 + l * 4);
#pragma unroll
        for (int j = 0; j < 8; ++j) {
            f32x4 tt = isE ? relu4(t[j] + qb) : t[j];
            acc += tt;
        }
    }
    for (; p < p1; ++p) {
        int g = se[p].x;
        f32x4 t = ld4(base + (size_t)g * 128 + l * 4);
        if (isE) t = relu4(t + qb);
        acc += t;
    }

    float inv = (p1 > p0) ? 1.f / (float)(p1 - p0) : 0.f;
    f32x4 m = {acc[0] * inv, acc[1] * inv, acc[2] * inv, acc[3] * inv};
    *(bf16x4*)(X + (size_t)n * 384 + 128 + (isE ? 128 : 0) + l * 4) = tobf4(m);

    // self features h1[n] -> X[:, 0:128] (bf16 -> bf16 direct copy)
    *(bf16x2*)(X + (size_t)n * 384 + lane * 2) =
        *(const bf16x2*)(h1 + (size_t)n * 128 + lane * 2);
}

// ---------------- node MLP: Y = relu(X[M,K] @ W[128,K]^T + b) ----------------
// swapped operands: lane stores contiguous f32x4 / bf16x4 (coalesced).
template <int K, bool SF32, bool SBF>
__global__ __launch_bounds__(256) void k_mlp_node(const __bf16* __restrict__ A,
                                                  const __bf16* __restrict__ W,
                                                  const float* __restrict__ bias,
                                                  __bf16* __restrict__ Ybf,
                                                  float* __restrict__ Yf,
                                                  int M) {
    const int wave = threadIdx.x >> 6;
    const int lane = threadIdx.x & 63;
    const int m0 = blockIdx.x * 128 + wave * 32;
    const int lr = lane & 15;
    const int kg = lane >> 4;

    f32x4 acc[2][8];
#pragma unroll
    for (int i = 0; i < 2; ++i)
#pragma unroll
        for (int j = 0; j < 8; ++j) acc[i][j] = (f32x4){0.f, 0.f, 0.f, 0.f};

    int r0 = m0 + lr;      if (r0 > M - 1) r0 = M - 1;
    int r1 = m0 + 16 + lr; if (r1 > M - 1) r1 = M - 1;
    const __bf16* px0 = A + (size_t)r0 * K + 8 * kg;
    const __bf16* px1 = A + (size_t)r1 * K + 8 * kg;
    const __bf16* pw  = W + (size_t)lr * K + 8 * kg;

#pragma unroll 4
    for (int k0 = 0; k0 < K; k0 += 32) {
        bf16x8 x0 = *(const bf16x8*)(px0 + k0);
        bf16x8 x1 = *(const bf16x8*)(px1 + k0);
#pragma unroll
        for (int j = 0; j < 8; ++j) {
            bf16x8 w = *(const bf16x8*)(pw + (size_t)j * 16 * K + k0);
            acc[0][j] = __builtin_amdgcn_mfma_f32_16x16x32_bf16(w, x0, acc[0][j], 0, 0, 0);
            acc[1][j] = __builtin_amdgcn_mfma_f32_16x16x32_bf16(w, x1, acc[1][j], 0, 0, 0);
        }
    }

#pragma unroll
    for (int i = 0; i < 2; ++i) {
        int node = m0 + i * 16 + lr;
        if (node >= M) continue;
#pragma unroll
        for (int j = 0; j < 8; ++j) {
            int ch0 = j * 16 + kg * 4;
            f32x4 bb = *(const f32x4*)(bias + ch0);
            f32x4 val = relu4(acc[i][j] + bb);
            if (SF32) *(f32x4*)(Yf + (size_t)node * 128 + ch0) = val;
            if (SBF)  *(bf16x4*)(Ybf + (size_t)node * 128 + ch0) = tobf4(val);
        }
    }
}

// ---------------- P/Q: P = H @ We[:, :128]^T,  Q = H @ We[:, 128:]^T  (bf16 out) ----------------
template <typename TI>
__global__ __launch_bounds__(256) void k_pq(const TI* __restrict__ H,
                                            const __bf16* __restrict__ We, /* [128,256] */
                                            __bf16* __restrict__ P,
                                            __bf16* __restrict__ Q) {
    const int wave = threadIdx.x >> 6;
    const int lane = threadIdx.x & 63;
    const int n0 = blockIdx.x * 64 + wave * 16;
    const int lr = lane & 15;
    const int kg = lane >> 4;

    f32x4 accP[8], accQ[8];
#pragma unroll
    for (int j = 0; j < 8; ++j) { accP[j] = (f32x4){0,0,0,0}; accQ[j] = (f32x4){0,0,0,0}; }

    int row = n0 + lr; if (row > NN - 1) row = NN - 1;
    const TI* ph = H + (size_t)row * 128 + 8 * kg;
    const __bf16* pw = We + (size_t)lr * 256 + 8 * kg;

#pragma unroll
    for (int k0 = 0; k0 < 128; k0 += 32) {
        bf16x8 h = ld8b(ph + k0);
#pragma unroll
        for (int j = 0; j < 8; ++j) {
            bf16x8 wp = *(const bf16x8*)(pw + (size_t)j * 16 * 256 + k0);
            bf16x8 wq = *(const bf16x8*)(pw + (size_t)j * 16 * 256 + 128 + k0);
            accP[j] = __builtin_amdgcn_mfma_f32_16x16x32_bf16(wp, h, accP[j], 0, 0, 0);
            accQ[j] = __builtin_amdgcn_mfma_f32_16x16x32_bf16(wq, h, accQ[j], 0, 0, 0);
        }
    }

    int node = n0 + lr;
    if (node < NN) {
#pragma unroll
        for (int j = 0; j < 8; ++j) {
            int ch0 = j * 16 + kg * 4;
            *(bf16x4*)(P + (size_t)node * 128 + ch0) = tobf4(accP[j]);
            *(bf16x4*)(Q + (size_t)node * 128 + ch0) = tobf4(accQ[j]);
        }
    }
}

// ---------------- final edge op: e2 = relu(P2[u] + Q2[v] + b2e), bf16 P/Q ----------------
__global__ __launch_bounds__(256) void k_add2(const __bf16* __restrict__ P,
                                              const __bf16* __restrict__ Q,
                                              const int* __restrict__ u,
                                              const int* __restrict__ v,
                                              const float* __restrict__ bias,
                                              float* __restrict__ out) {
    const int half = threadIdx.x >> 5;          // 0..7
    const int l = threadIdx.x & 31;
    const int e0 = blockIdx.x * 32 + half * 4;  // 32 edges/block, 4 per half-wave
    f32x4 bb = *(const f32x4*)(bias + l * 4);

    int uu[4], vv[4];
#pragma unroll
    for (int j = 0; j < 4; ++j) { uu[j] = u[e0 + j]; vv[j] = v[e0 + j]; }
    f32x4 pv[4], qv[4];
#pragma unroll
    for (int j = 0; j < 4; ++j) {
        pv[j] = ld4(P + (size_t)uu[j] * 128 + l * 4);
        qv[j] = ld4(Q + (size_t)vv[j] * 128 + l * 4);
    }
#pragma unroll
    for (int j = 0; j < 4; ++j)
        *(f32x4*)(out + (size_t)(e0 + j) * 128 + l * 4) = relu4(pv[j] + qv[j] + bb);
}

extern "C" void kernel_launch(void* const* d_in, const int* in_sizes, int n_in,
                              void* d_out, int out_size, void* d_ws, size_t ws_size,
                              hipStream_t stream) {
    const float* nfeats = (const float*)d_in[0];
    const float* efeats = (const float*)d_in[1];
    const int*   u      = (const int*)d_in[2];
    const int*   v      = (const int*)d_in[3];
    const float* W1a = (const float*)d_in[4];
    const float* b1a = (const float*)d_in[5];
    const float* W1e = (const float*)d_in[6];
    const float* b1e = (const float*)d_in[7];
    const float* W2a = (const float*)d_in[8];
    const float* b2a = (const float*)d_in[9];
    const float* W2e = (const float*)d_in[10];
    const float* b2e = (const float*)d_in[11];

    float* h2f = (float*)d_out;                       // [NN,128] f32 (output 0)
    float* e2f = h2f + (size_t)NN * 128;              // [NE,128] f32 (output 1)

    // e2 region (409.6 MB) is scratch until k_add2 writes it
    char* eb = (char*)e2f;
    __bf16* Xbuf = (__bf16*)(eb);                     // [NN,384]  38,400,000 B
    __bf16* h1bf = (__bf16*)(eb + 38400000);          // [NN,128]  12,800,000 B
    __bf16* P1   = (__bf16*)(eb + 51200000);          // [NN,128]  12,800,000 B
    __bf16* Q1   = (__bf16*)(eb + 64000000);          // [NN,128]  12,800,000 B
    int2*   se   = (int2*)  (eb + 76800000);          // [NE]       6,400,000 B

    char* w = (char*)d_ws;
    int* cnt = (int*)(w);                    // 200,000 B
    int* off = (int*)(w + 200000);           // 200,004 B (padded)
    int* cur = (int*)(w + 400016);           // 200,000 B
    __bf16* w1a = (__bf16*)(w + 600016);     // 98,304 B
    __bf16* w1e = (__bf16*)(w + 698320);     // 65,536 B
    __bf16* w2a = (__bf16*)(w + 763856);     // 98,304 B
    __bf16* w2e = (__bf16*)(w + 862160);     // 65,536 B
    __bf16* P2  = (__bf16*)(w + 927696);     // 12,800,000 B
    __bf16* Q2  = (__bf16*)(w + 13727696);   // 12,800,000 B (total ~26.5 MB)

    // CSR build (k_zero replaces hipMemsetAsync: rocclr fill took ~255us!)
    k_zero<<<(NN + 255) / 256, 256, 0, stream>>>(cnt);
    k_count<<<1024, 256, 0, stream>>>(v, cnt);
    k_scan<<<1, 1024, 0, stream>>>(cnt, off, cur);
    k_fill<<<1024, 256, 0, stream>>>(u, v, cur, se);

    // weights -> bf16
    k_cvtw<<<192, 256, 0, stream>>>(W1a, w1a, W1e, w1e, W2a, w2a, W2e, w2e);

    // layer 1
    k_agg1<<<NN / 4, 256, 0, stream>>>(nfeats, efeats, se, off, Xbuf);
    k_mlp_node<384, false, true><<<(NN + 127) / 128, 256, 0, stream>>>(Xbuf, w1a, b1a, h1bf, nullptr, NN);
    k_pq<__bf16><<<(NN + 63) / 64, 256, 0, stream>>>(h1bf, w1e, P1, Q1);

    // layer 2 (edge-MLP of layer 1 fused into aggregation)
    k_agg2<<<NN / 4, 256, 0, stream>>>(h1bf, P1, Q1, b1e, se, off, Xbuf);
    k_mlp_node<384, true, false><<<(NN + 127) / 128, 256, 0, stream>>>(Xbuf, w2a, b2a, nullptr, h2f, NN);
    k_pq<float><<<(NN + 63) / 64, 256, 0, stream>>>(h2f, w2e, P2, Q2);
    k_add2<<<NE / 32, 256, 0, stream>>>(P2, Q2, u, v, b2e, e2f);
}

// Round 5
// 665.876 us; speedup vs baseline: 2.1889x; 1.0912x over previous
//
#include <hip/hip_runtime.h>
#include <hip/hip_bf16.h>
#include <stdint.h>
#include <stddef.h>

#define NN 50000
#define NE 800000

typedef __attribute__((ext_vector_type(8))) __bf16 bf16x8;
typedef __attribute__((ext_vector_type(4))) __bf16 bf16x4;
typedef __attribute__((ext_vector_type(2))) __bf16 bf16x2;
typedef __attribute__((ext_vector_type(4))) float  f32x4;

static __device__ __forceinline__ f32x4 ld4(const float* p)  { return *(const f32x4*)p; }
static __device__ __forceinline__ f32x4 ld4(const __bf16* p) {
    bf16x4 v = *(const bf16x4*)p;
    return (f32x4){(float)v[0], (float)v[1], (float)v[2], (float)v[3]};
}
static __device__ __forceinline__ f32x4 ld4_nt(const float* p) {
    return __builtin_nontemporal_load((const f32x4*)p);
}
static __device__ __forceinline__ f32x4 relu4(f32x4 a) {
    return (f32x4){fmaxf(a[0], 0.f), fmaxf(a[1], 0.f), fmaxf(a[2], 0.f), fmaxf(a[3], 0.f)};
}
static __device__ __forceinline__ bf16x4 tobf4(f32x4 a) {
    bf16x4 o; o[0] = (__bf16)a[0]; o[1] = (__bf16)a[1]; o[2] = (__bf16)a[2]; o[3] = (__bf16)a[3];
    return o;
}

// ---------------- zero cnt + convert all four weight matrices (one launch) ----------------
__global__ __launch_bounds__(256) void k_zero_cvtw(int* __restrict__ cnt,
                                                   const float* __restrict__ a, __bf16* __restrict__ oa,
                                                   const float* __restrict__ b, __bf16* __restrict__ ob,
                                                   const float* __restrict__ c, __bf16* __restrict__ oc,
                                                   const float* __restrict__ d, __bf16* __restrict__ od) {
    int i = blockIdx.x * 256 + threadIdx.x;   // grid 256 -> 65536 threads
    if (i < NN) cnt[i] = 0;
    if (i < 128 * 384) { oa[i] = (__bf16)a[i]; oc[i] = (__bf16)c[i]; }
    if (i < 128 * 256) { ob[i] = (__bf16)b[i]; od[i] = (__bf16)d[i]; }
}

// ---------------- nfeats f32 -> bf16 (nf read exactly once afterwards from bf16) ----------------
__global__ __launch_bounds__(256) void k_cvtn(const float* __restrict__ nf, __bf16* __restrict__ nfbf) {
    int i = blockIdx.x * 256 + threadIdx.x;       // grid covers 800000 (x8 elems)
    int stride = gridDim.x * 256;
    for (; i < NN * 128 / 8; i += stride) {
        f32x4 a = __builtin_nontemporal_load((const f32x4*)(nf + (size_t)i * 8));
        f32x4 b = __builtin_nontemporal_load((const f32x4*)(nf + (size_t)i * 8 + 4));
        bf16x8 o;
        o[0] = (__bf16)a[0]; o[1] = (__bf16)a[1]; o[2] = (__bf16)a[2]; o[3] = (__bf16)a[3];
        o[4] = (__bf16)b[0]; o[5] = (__bf16)b[1]; o[6] = (__bf16)b[2]; o[7] = (__bf16)b[3];
        *(bf16x8*)(nfbf + (size_t)i * 8) = o;
    }
}

// ---------------- CSR build ----------------
__global__ __launch_bounds__(256) void k_count(const int* __restrict__ v, int* __restrict__ cnt) {
    int i = blockIdx.x * 256 + threadIdx.x;
    int stride = gridDim.x * 256;
    for (; i < NE; i += stride) atomicAdd(&cnt[v[i]], 1);
}

__global__ __launch_bounds__(1024) void k_scan(const int* __restrict__ cnt,
                                               int* __restrict__ off,
                                               int* __restrict__ cur) {
    __shared__ int sh[1024];
    const int T = 1024;
    const int C = (NN + T - 1) / T;
    int t = threadIdx.x;
    int base = t * C;
    int s = 0;
    for (int j = 0; j < C; ++j) {
        int idx = base + j;
        if (idx < NN) s += cnt[idx];
    }
    sh[t] = s;
    __syncthreads();
    for (int d = 1; d < T; d <<= 1) {
        int val = (t >= d) ? sh[t - d] : 0;
        __syncthreads();
        sh[t] += val;
        __syncthreads();
    }
    int run = sh[t] - s;
    for (int j = 0; j < C; ++j) {
        int idx = base + j;
        if (idx < NN) {
            off[idx] = run; cur[idx] = run;
            run += cnt[idx];
        }
    }
    if (t == T - 1) off[NN] = sh[T - 1];
}

__global__ __launch_bounds__(256) void k_fill(const int* __restrict__ u,
                                              const int* __restrict__ v,
                                              int* __restrict__ cur,
                                              int2* __restrict__ se) {
    int i = blockIdx.x * 256 + threadIdx.x;
    int stride = gridDim.x * 256;
    for (; i < NE; i += stride) {
        int pos = atomicAdd(&cur[v[i]], 1);
        se[pos] = make_int2(u[i], i);
    }
}

// ---------------- layer-1 aggregation: X1 = [nf, mean nf[u], mean ef] ----------------
// node gathers from bf16 nfbf (L2-resident); edge rows f32 nontemporal (read-once stream).
__global__ __launch_bounds__(256) void k_agg1(const __bf16* __restrict__ nfbf,
                                              const float* __restrict__ ef,
                                              const int2* __restrict__ se,
                                              const int* __restrict__ off,
                                              __bf16* __restrict__ X) {
    const int wid  = threadIdx.x >> 6;
    const int lane = threadIdx.x & 63;
    const int n = blockIdx.x * 4 + wid;
    const int p0 = __builtin_amdgcn_readfirstlane(off[n]);
    const int p1 = __builtin_amdgcn_readfirstlane(off[n + 1]);
    const bool isE = lane >= 32;
    const int l = lane & 31;

    f32x4 acc = {0.f, 0.f, 0.f, 0.f};
    int p = p0;
    for (; p + 8 <= p1; p += 8) {
        int2 g[8];
#pragma unroll
        for (int j = 0; j < 8; ++j) g[j] = se[p + j];
        f32x4 t[8];
        if (isE) {
#pragma unroll
            for (int j = 0; j < 8; ++j) t[j] = ld4_nt(ef + (size_t)g[j].y * 128 + l * 4);
        } else {
#pragma unroll
            for (int j = 0; j < 8; ++j) t[j] = ld4(nfbf + (size_t)g[j].x * 128 + l * 4);
        }
#pragma unroll
        for (int j = 0; j < 8; ++j) acc += t[j];
    }
    for (; p < p1; ++p) {
        int2 g = se[p];
        acc += isE ? ld4_nt(ef + (size_t)g.y * 128 + l * 4)
                   : ld4(nfbf + (size_t)g.x * 128 + l * 4);
    }

    float inv = (p1 > p0) ? 1.f / (float)(p1 - p0) : 0.f;
    f32x4 m = {acc[0] * inv, acc[1] * inv, acc[2] * inv, acc[3] * inv};
    *(bf16x4*)(X + (size_t)n * 384 + 128 + (isE ? 128 : 0) + l * 4) = tobf4(m);

    // self features (already bf16)
    *(bf16x2*)(X + (size_t)n * 384 + lane * 2) =
        *(const bf16x2*)(nfbf + (size_t)n * 128 + lane * 2);
}

// ---------------- layer-2 aggregation with fused layer-1 edge-MLP ----------------
// X2[n] = [h1[n], mean h1[u[e]], mean relu(P1[u[e]] + Q1[n] + b1e)]
__global__ __launch_bounds__(256) void k_agg2(const __bf16* __restrict__ h1,
                                              const __bf16* __restrict__ P1,
                                              const __bf16* __restrict__ Q1,
                                              const float* __restrict__ b1e,
                                              const int2* __restrict__ se,
                                              const int* __restrict__ off,
                                              __bf16* __restrict__ X) {
    const int wid  = threadIdx.x >> 6;
    const int lane = threadIdx.x & 63;
    const int n = blockIdx.x * 4 + wid;
    const int p0 = __builtin_amdgcn_readfirstlane(off[n]);
    const int p1 = __builtin_amdgcn_readfirstlane(off[n + 1]);
    const bool isE = lane >= 32;
    const int l = lane & 31;
    const __bf16* base = isE ? P1 : h1;

    f32x4 qb = ld4(Q1 + (size_t)n * 128 + l * 4) + ld4(b1e + l * 4);

    f32x4 acc = {0.f, 0.f, 0.f, 0.f};
    int p = p0;
    for (; p + 8 <= p1; p += 8) {
        int g[8];
#pragma unroll
        for (int j = 0; j < 8; ++j) g[j] = se[p + j].x;
        f32x4 t[8];
#pragma unroll
        for (int j = 0; j < 8; ++j) t[j] = ld4(base + (size_t)g[j] * 128 + l * 4);
#pragma unroll
        for (int j = 0; j < 8; ++j) {
            f32x4 tt = isE ? relu4(t[j] + qb) : t[j];
            acc += tt;
        }
    }
    for (; p < p1; ++p) {
        int g = se[p].x;
        f32x4 t = ld4(base + (size_t)g * 128 + l * 4);
        if (isE) t = relu4(t + qb);
        acc += t;
    }

    float inv = (p1 > p0) ? 1.f / (float)(p1 - p0) : 0.f;
    f32x4 m = {acc[0] * inv, acc[1] * inv, acc[2] * inv, acc[3] * inv};
    *(bf16x4*)(X + (size_t)n * 384 + 128 + (isE ? 128 : 0) + l * 4) = tobf4(m);

    *(bf16x2*)(X + (size_t)n * 384 + lane * 2) =
        *(const bf16x2*)(h1 + (size_t)n * 128 + lane * 2);
}

// ---------------- fused node MLP + P/Q projection ----------------
// h = relu(X[M,384] @ Wa^T + ba)  -> global (bf16 or f32) + per-wave LDS tile
// P = h @ We[:, :128]^T, Q = h @ We[:, 128:]^T -> bf16
template <bool HF32>
__global__ __launch_bounds__(256) void k_mlp_pq(const __bf16* __restrict__ A,
                                                const __bf16* __restrict__ Wa,
                                                const float* __restrict__ ba,
                                                const __bf16* __restrict__ We,
                                                __bf16* __restrict__ Hbf,
                                                float* __restrict__ Hf,
                                                __bf16* __restrict__ P,
                                                __bf16* __restrict__ Q,
                                                int M) {
    const int K = 384;
    const int wave = threadIdx.x >> 6;
    const int lane = threadIdx.x & 63;
    const int m0 = blockIdx.x * 128 + wave * 32;
    const int lr = lane & 15;
    const int kg = lane >> 4;

    __shared__ __bf16 hlds[4 * 32 * 136];   // per-wave [32][136] bf16, pad->conflict-free
    __bf16* my = hlds + wave * 32 * 136;

    f32x4 acc[2][8];
#pragma unroll
    for (int i = 0; i < 2; ++i)
#pragma unroll
        for (int j = 0; j < 8; ++j) acc[i][j] = (f32x4){0.f, 0.f, 0.f, 0.f};

    int r0 = m0 + lr;      if (r0 > M - 1) r0 = M - 1;
    int r1 = m0 + 16 + lr; if (r1 > M - 1) r1 = M - 1;
    const __bf16* px0 = A + (size_t)r0 * K + 8 * kg;
    const __bf16* px1 = A + (size_t)r1 * K + 8 * kg;
    const __bf16* pwa = Wa + (size_t)lr * K + 8 * kg;

#pragma unroll 4
    for (int k0 = 0; k0 < K; k0 += 32) {
        bf16x8 x0 = *(const bf16x8*)(px0 + k0);
        bf16x8 x1 = *(const bf16x8*)(px1 + k0);
#pragma unroll
        for (int j = 0; j < 8; ++j) {
            bf16x8 w = *(const bf16x8*)(pwa + (size_t)j * 16 * K + k0);
            acc[0][j] = __builtin_amdgcn_mfma_f32_16x16x32_bf16(w, x0, acc[0][j], 0, 0, 0);
            acc[1][j] = __builtin_amdgcn_mfma_f32_16x16x32_bf16(w, x1, acc[1][j], 0, 0, 0);
        }
    }

    // epilogue: store h + stage into LDS for the second GEMM
#pragma unroll
    for (int i = 0; i < 2; ++i) {
        int node = m0 + i * 16 + lr;
#pragma unroll
        for (int j = 0; j < 8; ++j) {
            int ch0 = j * 16 + kg * 4;
            f32x4 bb = *(const f32x4*)(ba + ch0);
            f32x4 val = relu4(acc[i][j] + bb);
            bf16x4 vb = tobf4(val);
            *(bf16x4*)(my + (i * 16 + lr) * 136 + ch0) = vb;
            if (node < M) {
                if (HF32) *(f32x4*)(Hf + (size_t)node * 128 + ch0) = val;
                else      *(bf16x4*)(Hbf + (size_t)node * 128 + ch0) = vb;
            }
        }
    }
    __syncthreads();

    // second GEMM: P/Q from LDS h-tile
    f32x4 accP[2][8], accQ[2][8];
#pragma unroll
    for (int i = 0; i < 2; ++i)
#pragma unroll
        for (int j = 0; j < 8; ++j) { accP[i][j] = (f32x4){0,0,0,0}; accQ[i][j] = (f32x4){0,0,0,0}; }

    const __bf16* pwe = We + (size_t)lr * 256 + 8 * kg;
#pragma unroll
    for (int k0 = 0; k0 < 128; k0 += 32) {
        bf16x8 h0 = *(const bf16x8*)(my + lr * 136 + k0 + 8 * kg);
        bf16x8 h1 = *(const bf16x8*)(my + (16 + lr) * 136 + k0 + 8 * kg);
#pragma unroll
        for (int j = 0; j < 8; ++j) {
            bf16x8 wp = *(const bf16x8*)(pwe + (size_t)j * 16 * 256 + k0);
            bf16x8 wq = *(const bf16x8*)(pwe + (size_t)j * 16 * 256 + 128 + k0);
            accP[0][j] = __builtin_amdgcn_mfma_f32_16x16x32_bf16(wp, h0, accP[0][j], 0, 0, 0);
            accP[1][j] = __builtin_amdgcn_mfma_f32_16x16x32_bf16(wp, h1, accP[1][j], 0, 0, 0);
            accQ[0][j] = __builtin_amdgcn_mfma_f32_16x16x32_bf16(wq, h0, accQ[0][j], 0, 0, 0);
            accQ[1][j] = __builtin_amdgcn_mfma_f32_16x16x32_bf16(wq, h1, accQ[1][j], 0, 0, 0);
        }
    }

#pragma unroll
    for (int i = 0; i < 2; ++i) {
        int node = m0 + i * 16 + lr;
        if (node >= M) continue;
#pragma unroll
        for (int j = 0; j < 8; ++j) {
            int ch0 = j * 16 + kg * 4;
            *(bf16x4*)(P + (size_t)node * 128 + ch0) = tobf4(accP[i][j]);
            *(bf16x4*)(Q + (size_t)node * 128 + ch0) = tobf4(accQ[i][j]);
        }
    }
}

// ---------------- final edge op: e2 = relu(P2[u] + Q2[v] + b2e), nontemporal stores ----------------
__global__ __launch_bounds__(256) void k_add2(const __bf16* __restrict__ P,
                                              const __bf16* __restrict__ Q,
                                              const int* __restrict__ u,
                                              const int* __restrict__ v,
                                              const float* __restrict__ bias,
                                              float* __restrict__ out) {
    const int half = threadIdx.x >> 5;          // 0..7
    const int l = threadIdx.x & 31;
    const int e0 = blockIdx.x * 64 + half * 8;  // 64 edges/block, 8 per half-wave
    f32x4 bb = *(const f32x4*)(bias + l * 4);

    int uu[8], vv[8];
#pragma unroll
    for (int j = 0; j < 8; ++j) { uu[j] = u[e0 + j]; vv[j] = v[e0 + j]; }
    f32x4 pv[8], qv[8];
#pragma unroll
    for (int j = 0; j < 8; ++j) {
        pv[j] = ld4(P + (size_t)uu[j] * 128 + l * 4);
        qv[j] = ld4(Q + (size_t)vv[j] * 128 + l * 4);
    }
#pragma unroll
    for (int j = 0; j < 8; ++j) {
        f32x4 r = relu4(pv[j] + qv[j] + bb);
        __builtin_nontemporal_store(r, (f32x4*)(out + (size_t)(e0 + j) * 128 + l * 4));
    }
}

extern "C" void kernel_launch(void* const* d_in, const int* in_sizes, int n_in,
                              void* d_out, int out_size, void* d_ws, size_t ws_size,
                              hipStream_t stream) {
    const float* nfeats = (const float*)d_in[0];
    const float* efeats = (const float*)d_in[1];
    const int*   u      = (const int*)d_in[2];
    const int*   v      = (const int*)d_in[3];
    const float* W1a = (const float*)d_in[4];
    const float* b1a = (const float*)d_in[5];
    const float* W1e = (const float*)d_in[6];
    const float* b1e = (const float*)d_in[7];
    const float* W2a = (const float*)d_in[8];
    const float* b2a = (const float*)d_in[9];
    const float* W2e = (const float*)d_in[10];
    const float* b2e = (const float*)d_in[11];

    float* h2f = (float*)d_out;                       // [NN,128] f32 (output 0)
    float* e2f = h2f + (size_t)NN * 128;              // [NE,128] f32 (output 1)

    // e2 region (409.6 MB) is scratch until k_add2 writes it
    char* eb = (char*)e2f;
    __bf16* Xbuf = (__bf16*)(eb);                     // [NN,384]  38,400,000 B
    __bf16* h1bf = (__bf16*)(eb + 38400000);          // [NN,128]  12,800,000 B
    __bf16* P1   = (__bf16*)(eb + 51200000);          // [NN,128]  12,800,000 B
    __bf16* Q1   = (__bf16*)(eb + 64000000);          // [NN,128]  12,800,000 B
    int2*   se   = (int2*)  (eb + 76800000);          // [NE]       6,400,000 B
    __bf16* nfbf = (__bf16*)(eb + 83200000);          // [NN,128]  12,800,000 B

    char* w = (char*)d_ws;
    int* cnt = (int*)(w);                    // 200,000 B
    int* off = (int*)(w + 200000);           // 200,004 B (padded)
    int* cur = (int*)(w + 400016);           // 200,000 B
    __bf16* w1a = (__bf16*)(w + 600016);     // 98,304 B
    __bf16* w1e = (__bf16*)(w + 698320);     // 65,536 B
    __bf16* w2a = (__bf16*)(w + 763856);     // 98,304 B
    __bf16* w2e = (__bf16*)(w + 862160);     // 65,536 B
    __bf16* P2  = (__bf16*)(w + 927696);     // 12,800,000 B
    __bf16* Q2  = (__bf16*)(w + 13727696);   // 12,800,000 B (total ~26.5 MB)

    // prep: zero cnt + weights->bf16 (1 launch), nfeats->bf16, CSR build
    k_zero_cvtw<<<256, 256, 0, stream>>>(cnt, W1a, w1a, W1e, w1e, W2a, w2a, W2e, w2e);
    k_cvtn<<<2048, 256, 0, stream>>>(nfeats, nfbf);
    k_count<<<1024, 256, 0, stream>>>(v, cnt);
    k_scan<<<1, 1024, 0, stream>>>(cnt, off, cur);
    k_fill<<<1024, 256, 0, stream>>>(u, v, cur, se);

    // layer 1
    k_agg1<<<NN / 4, 256, 0, stream>>>(nfbf, efeats, se, off, Xbuf);
    k_mlp_pq<false><<<(NN + 127) / 128, 256, 0, stream>>>(Xbuf, w1a, b1a, w1e, h1bf, nullptr, P1, Q1, NN);

    // layer 2 (layer-1 edge-MLP fused into aggregation)
    k_agg2<<<NN / 4, 256, 0, stream>>>(h1bf, P1, Q1, b1e, se, off, Xbuf);
    k_mlp_pq<true><<<(NN + 127) / 128, 256, 0, stream>>>(Xbuf, w2a, b2a, w2e, nullptr, h2f, P2, Q2, NN);
    k_add2<<<NE / 64, 256, 0, stream>>>(P2, Q2, u, v, b2e, e2f);
}

// Round 6
// 660.732 us; speedup vs baseline: 2.2060x; 1.0078x over previous
//
#include <hip/hip_runtime.h>
#include <hip/hip_bf16.h>
#include <stdint.h>
#include <stddef.h>

#define NN 50000
#define NE 800000

typedef __attribute__((ext_vector_type(8))) __bf16 bf16x8;
typedef __attribute__((ext_vector_type(4))) __bf16 bf16x4;
typedef __attribute__((ext_vector_type(2))) __bf16 bf16x2;
typedef __attribute__((ext_vector_type(4))) float  f32x4;

static __device__ __forceinline__ f32x4 ld4(const float* p)  { return *(const f32x4*)p; }
static __device__ __forceinline__ f32x4 ld4(const __bf16* p) {
    bf16x4 v = *(const bf16x4*)p;
    return (f32x4){(float)v[0], (float)v[1], (float)v[2], (float)v[3]};
}
static __device__ __forceinline__ f32x4 ld4_nt(const float* p) {
    return __builtin_nontemporal_load((const f32x4*)p);
}
static __device__ __forceinline__ f32x4 relu4(f32x4 a) {
    return (f32x4){fmaxf(a[0], 0.f), fmaxf(a[1], 0.f), fmaxf(a[2], 0.f), fmaxf(a[3], 0.f)};
}
static __device__ __forceinline__ bf16x4 tobf4(f32x4 a) {
    bf16x4 o; o[0] = (__bf16)a[0]; o[1] = (__bf16)a[1]; o[2] = (__bf16)a[2]; o[3] = (__bf16)a[3];
    return o;
}

// ---------------- prep: zero cnt + weights->bf16 + nfeats->bf16, one launch ----------------
__global__ __launch_bounds__(256) void k_prep(int* __restrict__ cnt,
                                              const float* __restrict__ a, __bf16* __restrict__ oa,
                                              const float* __restrict__ b, __bf16* __restrict__ ob,
                                              const float* __restrict__ c, __bf16* __restrict__ oc,
                                              const float* __restrict__ d, __bf16* __restrict__ od,
                                              const float* __restrict__ nf, __bf16* __restrict__ nfbf) {
    int i = blockIdx.x * 256 + threadIdx.x;       // grid 2048 -> 524288 threads
    if (i < NN) cnt[i] = 0;
    if (i < 128 * 384) { oa[i] = (__bf16)a[i]; oc[i] = (__bf16)c[i]; }
    if (i < 128 * 256) { ob[i] = (__bf16)b[i]; od[i] = (__bf16)d[i]; }
    int stride = gridDim.x * 256;
    for (int j = i; j < NN * 128 / 8; j += stride) {
        f32x4 x = __builtin_nontemporal_load((const f32x4*)(nf + (size_t)j * 8));
        f32x4 y = __builtin_nontemporal_load((const f32x4*)(nf + (size_t)j * 8 + 4));
        bf16x8 o;
        o[0] = (__bf16)x[0]; o[1] = (__bf16)x[1]; o[2] = (__bf16)x[2]; o[3] = (__bf16)x[3];
        o[4] = (__bf16)y[0]; o[5] = (__bf16)y[1]; o[6] = (__bf16)y[2]; o[7] = (__bf16)y[3];
        *(bf16x8*)(nfbf + (size_t)j * 8) = o;
    }
}

// ---------------- CSR build ----------------
__global__ __launch_bounds__(256) void k_count(const int* __restrict__ v, int* __restrict__ cnt) {
    int i = blockIdx.x * 256 + threadIdx.x;
    int stride = gridDim.x * 256;
    for (; i < NE; i += stride) atomicAdd(&cnt[v[i]], 1);
}

__global__ __launch_bounds__(1024) void k_scan(const int* __restrict__ cnt,
                                               int* __restrict__ off,
                                               int* __restrict__ cur) {
    __shared__ int sh[1024];
    const int T = 1024;
    const int C = (NN + T - 1) / T;
    int t = threadIdx.x;
    int base = t * C;
    int s = 0;
    for (int j = 0; j < C; ++j) {
        int idx = base + j;
        if (idx < NN) s += cnt[idx];
    }
    sh[t] = s;
    __syncthreads();
    for (int d = 1; d < T; d <<= 1) {
        int val = (t >= d) ? sh[t - d] : 0;
        __syncthreads();
        sh[t] += val;
        __syncthreads();
    }
    int run = sh[t] - s;
    for (int j = 0; j < C; ++j) {
        int idx = base + j;
        if (idx < NN) {
            off[idx] = run; cur[idx] = run;
            run += cnt[idx];
        }
    }
    if (t == T - 1) off[NN] = sh[T - 1];
}

__global__ __launch_bounds__(256) void k_fill(const int* __restrict__ u,
                                              const int* __restrict__ v,
                                              int* __restrict__ cur,
                                              int2* __restrict__ se) {
    int i = blockIdx.x * 256 + threadIdx.x;
    int stride = gridDim.x * 256;
    for (; i < NE; i += stride) {
        int pos = atomicAdd(&cur[v[i]], 1);
        se[pos] = make_int2(u[i], i);
    }
}

// ---------------- layer-1 aggregation: X1 = [nf, mean nf[u], mean ef] ----------------
__global__ __launch_bounds__(256) void k_agg1(const __bf16* __restrict__ nfbf,
                                              const float* __restrict__ ef,
                                              const int2* __restrict__ se,
                                              const int* __restrict__ off,
                                              __bf16* __restrict__ X) {
    const int wid  = threadIdx.x >> 6;
    const int lane = threadIdx.x & 63;
    const int n = blockIdx.x * 4 + wid;
    const int p0 = __builtin_amdgcn_readfirstlane(off[n]);
    const int p1 = __builtin_amdgcn_readfirstlane(off[n + 1]);
    const bool isE = lane >= 32;
    const int l = lane & 31;

    f32x4 acc = {0.f, 0.f, 0.f, 0.f};
    int p = p0;
    for (; p + 8 <= p1; p += 8) {
        int2 g[8];
#pragma unroll
        for (int j = 0; j < 8; ++j) g[j] = se[p + j];
        f32x4 t[8];
        if (isE) {
#pragma unroll
            for (int j = 0; j < 8; ++j) t[j] = ld4_nt(ef + (size_t)g[j].y * 128 + l * 4);
        } else {
#pragma unroll
            for (int j = 0; j < 8; ++j) t[j] = ld4(nfbf + (size_t)g[j].x * 128 + l * 4);
        }
#pragma unroll
        for (int j = 0; j < 8; ++j) acc += t[j];
    }
    for (; p < p1; ++p) {
        int2 g = se[p];
        acc += isE ? ld4_nt(ef + (size_t)g.y * 128 + l * 4)
                   : ld4(nfbf + (size_t)g.x * 128 + l * 4);
    }

    float inv = (p1 > p0) ? 1.f / (float)(p1 - p0) : 0.f;
    f32x4 m = {acc[0] * inv, acc[1] * inv, acc[2] * inv, acc[3] * inv};
    *(bf16x4*)(X + (size_t)n * 384 + 128 + (isE ? 128 : 0) + l * 4) = tobf4(m);

    // self features (already bf16)
    *(bf16x2*)(X + (size_t)n * 384 + lane * 2) =
        *(const bf16x2*)(nfbf + (size_t)n * 128 + lane * 2);
}

// ---------------- layer-2 aggregation, fused layer-1 edge-MLP ----------------
// HP1[n][256] = [h1[n] | P1[n]]  ->  full 64-lane wave gathers ONE 512B row per edge.
// X2[n] = [h1[n], mean h1[u[e]], mean relu(P1[u[e]] + Q1[n] + b1e)]
__global__ __launch_bounds__(256) void k_agg2(const __bf16* __restrict__ HP1,
                                              const __bf16* __restrict__ Q1,
                                              const float* __restrict__ b1e,
                                              const int2* __restrict__ se,
                                              const int* __restrict__ off,
                                              __bf16* __restrict__ X) {
    const int wid  = threadIdx.x >> 6;
    const int lane = threadIdx.x & 63;
    const int n = blockIdx.x * 4 + wid;
    const int p0 = __builtin_amdgcn_readfirstlane(off[n]);
    const int p1 = __builtin_amdgcn_readfirstlane(off[n + 1]);
    const bool isE = lane >= 32;                 // lanes 32-63 own the P-half of the row
    const int l = lane & 31;

    f32x4 qb = ld4(Q1 + (size_t)n * 128 + l * 4) + ld4(b1e + l * 4);

    f32x4 acc = {0.f, 0.f, 0.f, 0.f};
    int p = p0;
    for (; p + 8 <= p1; p += 8) {
        int g[8];
#pragma unroll
        for (int j = 0; j < 8; ++j) g[j] = se[p + j].x;
        f32x4 t[8];
#pragma unroll
        for (int j = 0; j < 8; ++j) t[j] = ld4(HP1 + (size_t)g[j] * 256 + lane * 4);
#pragma unroll
        for (int j = 0; j < 8; ++j) {
            f32x4 tt = isE ? relu4(t[j] + qb) : t[j];
            acc += tt;
        }
    }
    for (; p < p1; ++p) {
        int g = se[p].x;
        f32x4 t = ld4(HP1 + (size_t)g * 256 + lane * 4);
        if (isE) t = relu4(t + qb);
        acc += t;
    }

    float inv = (p1 > p0) ? 1.f / (float)(p1 - p0) : 0.f;
    f32x4 m = {acc[0] * inv, acc[1] * inv, acc[2] * inv, acc[3] * inv};
    *(bf16x4*)(X + (size_t)n * 384 + 128 + (isE ? 128 : 0) + l * 4) = tobf4(m);

    // self features h1[n] (h-half of HP1 row)
    *(bf16x2*)(X + (size_t)n * 384 + lane * 2) =
        *(const bf16x2*)(HP1 + (size_t)n * 256 + lane * 2);
}

// ---------------- fused node MLP + P/Q projection ----------------
// MODE 0 (layer 1): h,P -> HP1 interleaved bf16; Q -> Q1 bf16
// MODE 1 (layer 2): h -> Hf f32 (nontemporal, final output); P,Q -> P2,Q2 bf16
template <int MODE>
__global__ __launch_bounds__(256) void k_mlp_pq(const __bf16* __restrict__ A,
                                                const __bf16* __restrict__ Wa,
                                                const float* __restrict__ ba,
                                                const __bf16* __restrict__ We,
                                                __bf16* __restrict__ HP,
                                                __bf16* __restrict__ Q1,
                                                float* __restrict__ Hf,
                                                __bf16* __restrict__ P2,
                                                __bf16* __restrict__ Q2,
                                                int M) {
    const int K = 384;
    const int wave = threadIdx.x >> 6;
    const int lane = threadIdx.x & 63;
    const int m0 = blockIdx.x * 128 + wave * 32;
    const int lr = lane & 15;
    const int kg = lane >> 4;

    __shared__ __bf16 hlds[4 * 32 * 136];   // per-wave [32][136] bf16
    __bf16* my = hlds + wave * 32 * 136;

    f32x4 acc[2][8];
#pragma unroll
    for (int i = 0; i < 2; ++i)
#pragma unroll
        for (int j = 0; j < 8; ++j) acc[i][j] = (f32x4){0.f, 0.f, 0.f, 0.f};

    int r0 = m0 + lr;      if (r0 > M - 1) r0 = M - 1;
    int r1 = m0 + 16 + lr; if (r1 > M - 1) r1 = M - 1;
    const __bf16* px0 = A + (size_t)r0 * K + 8 * kg;
    const __bf16* px1 = A + (size_t)r1 * K + 8 * kg;
    const __bf16* pwa = Wa + (size_t)lr * K + 8 * kg;

#pragma unroll 4
    for (int k0 = 0; k0 < K; k0 += 32) {
        bf16x8 x0 = *(const bf16x8*)(px0 + k0);
        bf16x8 x1 = *(const bf16x8*)(px1 + k0);
#pragma unroll
        for (int j = 0; j < 8; ++j) {
            bf16x8 w = *(const bf16x8*)(pwa + (size_t)j * 16 * K + k0);
            acc[0][j] = __builtin_amdgcn_mfma_f32_16x16x32_bf16(w, x0, acc[0][j], 0, 0, 0);
            acc[1][j] = __builtin_amdgcn_mfma_f32_16x16x32_bf16(w, x1, acc[1][j], 0, 0, 0);
        }
    }

    // epilogue: store h + stage into LDS for the P/Q GEMM
#pragma unroll
    for (int i = 0; i < 2; ++i) {
        int node = m0 + i * 16 + lr;
#pragma unroll
        for (int j = 0; j < 8; ++j) {
            int ch0 = j * 16 + kg * 4;
            f32x4 bb = *(const f32x4*)(ba + ch0);
            f32x4 val = relu4(acc[i][j] + bb);
            bf16x4 vb = tobf4(val);
            *(bf16x4*)(my + (i * 16 + lr) * 136 + ch0) = vb;
            if (node < M) {
                if (MODE == 0) *(bf16x4*)(HP + (size_t)node * 256 + ch0) = vb;
                else __builtin_nontemporal_store(val, (f32x4*)(Hf + (size_t)node * 128 + ch0));
            }
        }
    }
    __syncthreads();

    // second GEMM: P/Q from LDS h-tile
    f32x4 accP[2][8], accQ[2][8];
#pragma unroll
    for (int i = 0; i < 2; ++i)
#pragma unroll
        for (int j = 0; j < 8; ++j) { accP[i][j] = (f32x4){0,0,0,0}; accQ[i][j] = (f32x4){0,0,0,0}; }

    const __bf16* pwe = We + (size_t)lr * 256 + 8 * kg;
#pragma unroll
    for (int k0 = 0; k0 < 128; k0 += 32) {
        bf16x8 h0 = *(const bf16x8*)(my + lr * 136 + k0 + 8 * kg);
        bf16x8 h1 = *(const bf16x8*)(my + (16 + lr) * 136 + k0 + 8 * kg);
#pragma unroll
        for (int j = 0; j < 8; ++j) {
            bf16x8 wp = *(const bf16x8*)(pwe + (size_t)j * 16 * 256 + k0);
            bf16x8 wq = *(const bf16x8*)(pwe + (size_t)j * 16 * 256 + 128 + k0);
            accP[0][j] = __builtin_amdgcn_mfma_f32_16x16x32_bf16(wp, h0, accP[0][j], 0, 0, 0);
            accP[1][j] = __builtin_amdgcn_mfma_f32_16x16x32_bf16(wp, h1, accP[1][j], 0, 0, 0);
            accQ[0][j] = __builtin_amdgcn_mfma_f32_16x16x32_bf16(wq, h0, accQ[0][j], 0, 0, 0);
            accQ[1][j] = __builtin_amdgcn_mfma_f32_16x16x32_bf16(wq, h1, accQ[1][j], 0, 0, 0);
        }
    }

#pragma unroll
    for (int i = 0; i < 2; ++i) {
        int node = m0 + i * 16 + lr;
        if (node >= M) continue;
#pragma unroll
        for (int j = 0; j < 8; ++j) {
            int ch0 = j * 16 + kg * 4;
            if (MODE == 0) {
                *(bf16x4*)(HP + (size_t)node * 256 + 128 + ch0) = tobf4(accP[i][j]);
                *(bf16x4*)(Q1 + (size_t)node * 128 + ch0)       = tobf4(accQ[i][j]);
            } else {
                *(bf16x4*)(P2 + (size_t)node * 128 + ch0) = tobf4(accP[i][j]);
                *(bf16x4*)(Q2 + (size_t)node * 128 + ch0) = tobf4(accQ[i][j]);
            }
        }
    }
}

// ---------------- final edge op: e2 = relu(P2[u] + Q2[v] + b2e) ----------------
__global__ __launch_bounds__(256) void k_add2(const __bf16* __restrict__ P,
                                              const __bf16* __restrict__ Q,
                                              const int* __restrict__ u,
                                              const int* __restrict__ v,
                                              const float* __restrict__ bias,
                                              float* __restrict__ out) {
    const int half = threadIdx.x >> 5;          // 0..7
    const int l = threadIdx.x & 31;
    const int e0 = blockIdx.x * 64 + half * 8;  // 64 edges/block, 8 per half-wave
    f32x4 bb = *(const f32x4*)(bias + l * 4);

    int uu[8], vv[8];
#pragma unroll
    for (int j = 0; j < 8; ++j) {
        uu[j] = __builtin_nontemporal_load(u + e0 + j);
        vv[j] = __builtin_nontemporal_load(v + e0 + j);
    }
    f32x4 pv[8], qv[8];
#pragma unroll
    for (int j = 0; j < 8; ++j) {
        pv[j] = ld4(P + (size_t)uu[j] * 128 + l * 4);
        qv[j] = ld4(Q + (size_t)vv[j] * 128 + l * 4);
    }
#pragma unroll
    for (int j = 0; j < 8; ++j) {
        f32x4 r = relu4(pv[j] + qv[j] + bb);
        __builtin_nontemporal_store(r, (f32x4*)(out + (size_t)(e0 + j) * 128 + l * 4));
    }
}

extern "C" void kernel_launch(void* const* d_in, const int* in_sizes, int n_in,
                              void* d_out, int out_size, void* d_ws, size_t ws_size,
                              hipStream_t stream) {
    const float* nfeats = (const float*)d_in[0];
    const float* efeats = (const float*)d_in[1];
    const int*   u      = (const int*)d_in[2];
    const int*   v      = (const int*)d_in[3];
    const float* W1a = (const float*)d_in[4];
    const float* b1a = (const float*)d_in[5];
    const float* W1e = (const float*)d_in[6];
    const float* b1e = (const float*)d_in[7];
    const float* W2a = (const float*)d_in[8];
    const float* b2a = (const float*)d_in[9];
    const float* W2e = (const float*)d_in[10];
    const float* b2e = (const float*)d_in[11];

    float* h2f = (float*)d_out;                       // [NN,128] f32 (output 0)
    float* e2f = h2f + (size_t)NN * 128;              // [NE,128] f32 (output 1)

    // e2 region (409.6 MB) is scratch until k_add2 writes it
    char* eb = (char*)e2f;
    __bf16* Xbuf = (__bf16*)(eb);                     // [NN,384]  38,400,000 B
    __bf16* HP1  = (__bf16*)(eb + 38400000);          // [NN,256]  25,600,000 B (h1|P1)
    __bf16* Q1   = (__bf16*)(eb + 64000000);          // [NN,128]  12,800,000 B
    int2*   se   = (int2*)  (eb + 76800000);          // [NE]       6,400,000 B
    __bf16* nfbf = (__bf16*)(eb + 83200000);          // [NN,128]  12,800,000 B

    char* w = (char*)d_ws;
    int* cnt = (int*)(w);                    // 200,000 B
    int* off = (int*)(w + 200000);           // 200,004 B (padded)
    int* cur = (int*)(w + 400016);           // 200,000 B
    __bf16* w1a = (__bf16*)(w + 600016);     // 98,304 B
    __bf16* w1e = (__bf16*)(w + 698320);     // 65,536 B
    __bf16* w2a = (__bf16*)(w + 763856);     // 98,304 B
    __bf16* w2e = (__bf16*)(w + 862160);     // 65,536 B
    __bf16* P2  = (__bf16*)(w + 927696);     // 12,800,000 B
    __bf16* Q2  = (__bf16*)(w + 13727696);   // 12,800,000 B (total ~26.5 MB)

    // prep (one launch) + CSR build
    k_prep<<<2048, 256, 0, stream>>>(cnt, W1a, w1a, W1e, w1e, W2a, w2a, W2e, w2e, nfeats, nfbf);
    k_count<<<1024, 256, 0, stream>>>(v, cnt);
    k_scan<<<1, 1024, 0, stream>>>(cnt, off, cur);
    k_fill<<<1024, 256, 0, stream>>>(u, v, cur, se);

    // layer 1
    k_agg1<<<NN / 4, 256, 0, stream>>>(nfbf, efeats, se, off, Xbuf);
    k_mlp_pq<0><<<(NN + 127) / 128, 256, 0, stream>>>(Xbuf, w1a, b1a, w1e, HP1, Q1, nullptr, nullptr, nullptr, NN);

    // layer 2 (layer-1 edge-MLP fused into aggregation, single 512B row gather per edge)
    k_agg2<<<NN / 4, 256, 0, stream>>>(HP1, Q1, b1e, se, off, Xbuf);
    k_mlp_pq<1><<<(NN + 127) / 128, 256, 0, stream>>>(Xbuf, w2a, b2a, w2e, nullptr, nullptr, h2f, P2, Q2, NN);
    k_add2<<<NE / 64, 256, 0, stream>>>(P2, Q2, u, v, b2e, e2f);
}

// Round 7
// 599.808 us; speedup vs baseline: 2.4300x; 1.1016x over previous
//
#include <hip/hip_runtime.h>
#include <hip/hip_bf16.h>
#include <stdint.h>
#include <stddef.h>

#define NN 50000
#define NE 800000

typedef __attribute__((ext_vector_type(8))) __bf16 bf16x8;
typedef __attribute__((ext_vector_type(4))) __bf16 bf16x4;
typedef __attribute__((ext_vector_type(2))) __bf16 bf16x2;
typedef __attribute__((ext_vector_type(4))) float  f32x4;

static __device__ __forceinline__ f32x4 ld4(const float* p)  { return *(const f32x4*)p; }
static __device__ __forceinline__ f32x4 ld4(const __bf16* p) {
    bf16x4 v = *(const bf16x4*)p;
    return (f32x4){(float)v[0], (float)v[1], (float)v[2], (float)v[3]};
}
static __device__ __forceinline__ f32x4 ld4_nt(const float* p) {
    return __builtin_nontemporal_load((const f32x4*)p);
}
static __device__ __forceinline__ f32x4 relu4(f32x4 a) {
    return (f32x4){fmaxf(a[0], 0.f), fmaxf(a[1], 0.f), fmaxf(a[2], 0.f), fmaxf(a[3], 0.f)};
}
static __device__ __forceinline__ bf16x4 tobf4(f32x4 a) {
    bf16x4 o; o[0] = (__bf16)a[0]; o[1] = (__bf16)a[1]; o[2] = (__bf16)a[2]; o[3] = (__bf16)a[3];
    return o;
}

// ---------------- prep: zero cnt + weights->bf16 + nfeats->bf16, one launch ----------------
__global__ __launch_bounds__(256) void k_prep(int* __restrict__ cnt,
                                              const float* __restrict__ a, __bf16* __restrict__ oa,
                                              const float* __restrict__ b, __bf16* __restrict__ ob,
                                              const float* __restrict__ c, __bf16* __restrict__ oc,
                                              const float* __restrict__ d, __bf16* __restrict__ od,
                                              const float* __restrict__ nf, __bf16* __restrict__ nfbf) {
    int i = blockIdx.x * 256 + threadIdx.x;       // grid 2048 -> 524288 threads
    if (i < NN) cnt[i] = 0;
    if (i < 128 * 384) { oa[i] = (__bf16)a[i]; oc[i] = (__bf16)c[i]; }
    if (i < 128 * 256) { ob[i] = (__bf16)b[i]; od[i] = (__bf16)d[i]; }
    int stride = gridDim.x * 256;
    for (int j = i; j < NN * 128 / 8; j += stride) {
        f32x4 x = __builtin_nontemporal_load((const f32x4*)(nf + (size_t)j * 8));
        f32x4 y = __builtin_nontemporal_load((const f32x4*)(nf + (size_t)j * 8 + 4));
        bf16x8 o;
        o[0] = (__bf16)x[0]; o[1] = (__bf16)x[1]; o[2] = (__bf16)x[2]; o[3] = (__bf16)x[3];
        o[4] = (__bf16)y[0]; o[5] = (__bf16)y[1]; o[6] = (__bf16)y[2]; o[7] = (__bf16)y[3];
        *(bf16x8*)(nfbf + (size_t)j * 8) = o;
    }
}

// ---------------- CSR build ----------------
__global__ __launch_bounds__(256) void k_count(const int* __restrict__ v, int* __restrict__ cnt) {
    int i = blockIdx.x * 256 + threadIdx.x;
    int stride = gridDim.x * 256;
    for (; i < NE; i += stride) atomicAdd(&cnt[v[i]], 1);
}

// parallel scan, 3 stages (replaces single-block k_scan: 1 CU + uncoalesced loads)
__global__ __launch_bounds__(1024) void k_scanA(const int* __restrict__ cnt, int* __restrict__ bsum) {
    __shared__ int sh[1024];
    int b = blockIdx.x;                 // 0..48
    int t = threadIdx.x;
    int idx = b * 1024 + t;
    int val = (idx < NN) ? cnt[idx] : 0;
    sh[t] = val;
    __syncthreads();
    for (int d = 512; d > 0; d >>= 1) {
        if (t < d) sh[t] += sh[t + d];
        __syncthreads();
    }
    if (t == 0) bsum[b] = sh[0];
}

__global__ __launch_bounds__(64) void k_scanB(const int* __restrict__ bsum,
                                              int* __restrict__ boff,
                                              int* __restrict__ off) {
    int lane = threadIdx.x;             // one wave
    int s = (lane < 49) ? bsum[lane] : 0;
    int incl = s;
    for (int d = 1; d < 64; d <<= 1) {
        int x = __shfl_up(incl, d);
        if (lane >= d) incl += x;
    }
    if (lane < 49) boff[lane] = incl - s;
    if (lane == 48) off[NN] = incl;
}

__global__ __launch_bounds__(1024) void k_scanC(const int* __restrict__ cnt,
                                                const int* __restrict__ boff,
                                                int* __restrict__ off,
                                                int* __restrict__ cur) {
    __shared__ int sh[1024];
    int b = blockIdx.x;
    int t = threadIdx.x;
    int idx = b * 1024 + t;
    int val = (idx < NN) ? cnt[idx] : 0;
    sh[t] = val;
    __syncthreads();
    for (int d = 1; d < 1024; d <<= 1) {
        int x = (t >= d) ? sh[t - d] : 0;
        __syncthreads();
        sh[t] += x;
        __syncthreads();
    }
    int excl = sh[t] - val + boff[b];
    if (idx < NN) { off[idx] = excl; cur[idx] = excl; }
}

__global__ __launch_bounds__(256) void k_fill(const int* __restrict__ u,
                                              const int* __restrict__ v,
                                              int* __restrict__ cur,
                                              int2* __restrict__ se) {
    int i = blockIdx.x * 256 + threadIdx.x;
    int stride = gridDim.x * 256;
    for (; i < NE; i += stride) {
        int pos = atomicAdd(&cur[v[i]], 1);
        se[pos] = make_int2(u[i], i);
    }
}

// ---------------- layer-1 aggregation: X1 = [nf, mean nf[u], mean ef] ----------------
__global__ __launch_bounds__(256) void k_agg1(const __bf16* __restrict__ nfbf,
                                              const float* __restrict__ ef,
                                              const int2* __restrict__ se,
                                              const int* __restrict__ off,
                                              __bf16* __restrict__ X) {
    const int wid  = threadIdx.x >> 6;
    const int lane = threadIdx.x & 63;
    const int n = blockIdx.x * 4 + wid;
    const int p0 = __builtin_amdgcn_readfirstlane(off[n]);
    const int p1 = __builtin_amdgcn_readfirstlane(off[n + 1]);
    const bool isE = lane >= 32;
    const int l = lane & 31;

    f32x4 acc = {0.f, 0.f, 0.f, 0.f};
    int p = p0;
    for (; p + 8 <= p1; p += 8) {
        int2 g[8];
#pragma unroll
        for (int j = 0; j < 8; ++j) g[j] = se[p + j];
        f32x4 t[8];
        if (isE) {
#pragma unroll
            for (int j = 0; j < 8; ++j) t[j] = ld4_nt(ef + (size_t)g[j].y * 128 + l * 4);
        } else {
#pragma unroll
            for (int j = 0; j < 8; ++j) t[j] = ld4(nfbf + (size_t)g[j].x * 128 + l * 4);
        }
#pragma unroll
        for (int j = 0; j < 8; ++j) acc += t[j];
    }
    for (; p < p1; ++p) {
        int2 g = se[p];
        acc += isE ? ld4_nt(ef + (size_t)g.y * 128 + l * 4)
                   : ld4(nfbf + (size_t)g.x * 128 + l * 4);
    }

    float inv = (p1 > p0) ? 1.f / (float)(p1 - p0) : 0.f;
    f32x4 m = {acc[0] * inv, acc[1] * inv, acc[2] * inv, acc[3] * inv};
    *(bf16x4*)(X + (size_t)n * 384 + 128 + (isE ? 128 : 0) + l * 4) = tobf4(m);

    // self features (already bf16)
    *(bf16x2*)(X + (size_t)n * 384 + lane * 2) =
        *(const bf16x2*)(nfbf + (size_t)n * 128 + lane * 2);
}

// ---------------- layer-2 aggregation, fused layer-1 edge-MLP ----------------
// HP1[n][256] = [h1[n] | P1[n]]; Q1 is pre-biased (b1e folded in).
// X2[n] = [h1[n], mean h1[u[e]], mean relu(P1[u[e]] + Q1[n])]
__global__ __launch_bounds__(256) void k_agg2(const __bf16* __restrict__ HP1,
                                              const __bf16* __restrict__ Q1,
                                              const int2* __restrict__ se,
                                              const int* __restrict__ off,
                                              __bf16* __restrict__ X) {
    const int wid  = threadIdx.x >> 6;
    const int lane = threadIdx.x & 63;
    const int n = blockIdx.x * 4 + wid;
    const int p0 = __builtin_amdgcn_readfirstlane(off[n]);
    const int p1 = __builtin_amdgcn_readfirstlane(off[n + 1]);
    const bool isE = lane >= 32;                 // lanes 32-63 own the P-half of the row
    const int l = lane & 31;

    f32x4 qb = ld4(Q1 + (size_t)n * 128 + l * 4);   // bias already folded

    f32x4 acc = {0.f, 0.f, 0.f, 0.f};
    int p = p0;
    for (; p + 8 <= p1; p += 8) {
        int g[8];
#pragma unroll
        for (int j = 0; j < 8; ++j) g[j] = se[p + j].x;
        f32x4 t[8];
#pragma unroll
        for (int j = 0; j < 8; ++j) t[j] = ld4(HP1 + (size_t)g[j] * 256 + lane * 4);
#pragma unroll
        for (int j = 0; j < 8; ++j) {
            f32x4 tt = isE ? relu4(t[j] + qb) : t[j];
            acc += tt;
        }
    }
    for (; p < p1; ++p) {
        int g = se[p].x;
        f32x4 t = ld4(HP1 + (size_t)g * 256 + lane * 4);
        if (isE) t = relu4(t + qb);
        acc += t;
    }

    float inv = (p1 > p0) ? 1.f / (float)(p1 - p0) : 0.f;
    f32x4 m = {acc[0] * inv, acc[1] * inv, acc[2] * inv, acc[3] * inv};
    *(bf16x4*)(X + (size_t)n * 384 + 128 + (isE ? 128 : 0) + l * 4) = tobf4(m);

    // self features h1[n] (h-half of HP1 row)
    *(bf16x2*)(X + (size_t)n * 384 + lane * 2) =
        *(const bf16x2*)(HP1 + (size_t)n * 256 + lane * 2);
}

// ---------------- fused node MLP + P/Q projection (64-row blocks, wave owns 16 rows) ----------------
// MODE 0 (layer 1): h,P -> HP1 interleaved bf16; Q+be -> Q1 bf16
// MODE 1 (layer 2): h -> Hf f32 (nontemporal, final output); P -> P2, Q+be -> Q2 bf16
template <int MODE>
__global__ __launch_bounds__(256) void k_mlp_pq(const __bf16* __restrict__ A,
                                                const __bf16* __restrict__ Wa,
                                                const float* __restrict__ ba,
                                                const __bf16* __restrict__ We,
                                                const float* __restrict__ be,
                                                __bf16* __restrict__ HP,
                                                __bf16* __restrict__ Q1,
                                                float* __restrict__ Hf,
                                                __bf16* __restrict__ P2,
                                                __bf16* __restrict__ Q2,
                                                int M) {
    const int K = 384;
    const int wave = threadIdx.x >> 6;
    const int lane = threadIdx.x & 63;
    const int m0 = blockIdx.x * 64 + wave * 16;
    const int lr = lane & 15;
    const int kg = lane >> 4;

    __shared__ __bf16 hlds[4 * 16 * 136];   // per-wave [16][136] bf16
    __bf16* my = hlds + wave * 16 * 136;

    f32x4 acc[8];
#pragma unroll
    for (int j = 0; j < 8; ++j) acc[j] = (f32x4){0.f, 0.f, 0.f, 0.f};

    int r0 = m0 + lr; if (r0 > M - 1) r0 = M - 1;
    const __bf16* px0 = A + (size_t)r0 * K + 8 * kg;
    const __bf16* pwa = Wa + (size_t)lr * K + 8 * kg;

#pragma unroll 4
    for (int k0 = 0; k0 < K; k0 += 32) {
        bf16x8 x0 = *(const bf16x8*)(px0 + k0);
#pragma unroll
        for (int j = 0; j < 8; ++j) {
            bf16x8 w = *(const bf16x8*)(pwa + (size_t)j * 16 * K + k0);
            acc[j] = __builtin_amdgcn_mfma_f32_16x16x32_bf16(w, x0, acc[j], 0, 0, 0);
        }
    }

    // epilogue: store h + stage into LDS for the P/Q GEMM
    {
        int node = m0 + lr;
#pragma unroll
        for (int j = 0; j < 8; ++j) {
            int ch0 = j * 16 + kg * 4;
            f32x4 bb = *(const f32x4*)(ba + ch0);
            f32x4 val = relu4(acc[j] + bb);
            bf16x4 vb = tobf4(val);
            *(bf16x4*)(my + lr * 136 + ch0) = vb;
            if (node < M) {
                if (MODE == 0) *(bf16x4*)(HP + (size_t)node * 256 + ch0) = vb;
                else __builtin_nontemporal_store(val, (f32x4*)(Hf + (size_t)node * 128 + ch0));
            }
        }
    }
    __syncthreads();

    // second GEMM: P/Q from LDS h-tile (16 rows)
    f32x4 accP[8], accQ[8];
#pragma unroll
    for (int j = 0; j < 8; ++j) { accP[j] = (f32x4){0,0,0,0}; accQ[j] = (f32x4){0,0,0,0}; }

    const __bf16* pwe = We + (size_t)lr * 256 + 8 * kg;
#pragma unroll
    for (int k0 = 0; k0 < 128; k0 += 32) {
        bf16x8 h0 = *(const bf16x8*)(my + lr * 136 + k0 + 8 * kg);
#pragma unroll
        for (int j = 0; j < 8; ++j) {
            bf16x8 wp = *(const bf16x8*)(pwe + (size_t)j * 16 * 256 + k0);
            bf16x8 wq = *(const bf16x8*)(pwe + (size_t)j * 16 * 256 + 128 + k0);
            accP[j] = __builtin_amdgcn_mfma_f32_16x16x32_bf16(wp, h0, accP[j], 0, 0, 0);
            accQ[j] = __builtin_amdgcn_mfma_f32_16x16x32_bf16(wq, h0, accQ[j], 0, 0, 0);
        }
    }

    int node = m0 + lr;
    if (node < M) {
#pragma unroll
        for (int j = 0; j < 8; ++j) {
            int ch0 = j * 16 + kg * 4;
            f32x4 bq = *(const f32x4*)(be + ch0);     // fold edge-bias into Q
            if (MODE == 0) {
                *(bf16x4*)(HP + (size_t)node * 256 + 128 + ch0) = tobf4(accP[j]);
                *(bf16x4*)(Q1 + (size_t)node * 128 + ch0)       = tobf4(accQ[j] + bq);
            } else {
                *(bf16x4*)(P2 + (size_t)node * 128 + ch0) = tobf4(accP[j]);
                *(bf16x4*)(Q2 + (size_t)node * 128 + ch0) = tobf4(accQ[j] + bq);
            }
        }
    }
}

// ---------------- final edge op: e2 = relu(P2[u] + Q2[v]), Q2 pre-biased ----------------
__global__ __launch_bounds__(256) void k_add2(const __bf16* __restrict__ P,
                                              const __bf16* __restrict__ Q,
                                              const int* __restrict__ u,
                                              const int* __restrict__ v,
                                              float* __restrict__ out) {
    const int half = threadIdx.x >> 5;          // 0..7
    const int l = threadIdx.x & 31;
    const int e0 = blockIdx.x * 64 + half * 8;  // 64 edges/block, 8 per half-wave

    int uu[8], vv[8];
#pragma unroll
    for (int j = 0; j < 8; ++j) {
        uu[j] = __builtin_nontemporal_load(u + e0 + j);
        vv[j] = __builtin_nontemporal_load(v + e0 + j);
    }
    f32x4 pv[8], qv[8];
#pragma unroll
    for (int j = 0; j < 8; ++j) {
        pv[j] = ld4(P + (size_t)uu[j] * 128 + l * 4);
        qv[j] = ld4(Q + (size_t)vv[j] * 128 + l * 4);
    }
#pragma unroll
    for (int j = 0; j < 8; ++j) {
        f32x4 r = relu4(pv[j] + qv[j]);
        __builtin_nontemporal_store(r, (f32x4*)(out + (size_t)(e0 + j) * 128 + l * 4));
    }
}

extern "C" void kernel_launch(void* const* d_in, const int* in_sizes, int n_in,
                              void* d_out, int out_size, void* d_ws, size_t ws_size,
                              hipStream_t stream) {
    const float* nfeats = (const float*)d_in[0];
    const float* efeats = (const float*)d_in[1];
    const int*   u      = (const int*)d_in[2];
    const int*   v      = (const int*)d_in[3];
    const float* W1a = (const float*)d_in[4];
    const float* b1a = (const float*)d_in[5];
    const float* W1e = (const float*)d_in[6];
    const float* b1e = (const float*)d_in[7];
    const float* W2a = (const float*)d_in[8];
    const float* b2a = (const float*)d_in[9];
    const float* W2e = (const float*)d_in[10];
    const float* b2e = (const float*)d_in[11];

    float* h2f = (float*)d_out;                       // [NN,128] f32 (output 0)
    float* e2f = h2f + (size_t)NN * 128;              // [NE,128] f32 (output 1)

    // e2 region (409.6 MB) is scratch until k_add2 writes it
    char* eb = (char*)e2f;
    __bf16* Xbuf = (__bf16*)(eb);                     // [NN,384]  38,400,000 B
    __bf16* HP1  = (__bf16*)(eb + 38400000);          // [NN,256]  25,600,000 B (h1|P1)
    __bf16* Q1   = (__bf16*)(eb + 64000000);          // [NN,128]  12,800,000 B
    int2*   se   = (int2*)  (eb + 76800000);          // [NE]       6,400,000 B
    __bf16* nfbf = (__bf16*)(eb + 83200000);          // [NN,128]  12,800,000 B

    char* w = (char*)d_ws;
    int* cnt  = (int*)(w);                   // 200,000 B
    int* off  = (int*)(w + 200000);          // 200,004 B (padded)
    int* cur  = (int*)(w + 400016);          // 200,000 B
    int* bsum = (int*)(w + 600016);          // 196 B (pad 256)
    int* boff = (int*)(w + 600272);          // 196 B (pad 256)
    __bf16* w1a = (__bf16*)(w + 600528);     // 98,304 B
    __bf16* w1e = (__bf16*)(w + 698832);     // 65,536 B
    __bf16* w2a = (__bf16*)(w + 764368);     // 98,304 B
    __bf16* w2e = (__bf16*)(w + 862672);     // 65,536 B
    __bf16* P2  = (__bf16*)(w + 928208);     // 12,800,000 B
    __bf16* Q2  = (__bf16*)(w + 13728208);   // 12,800,000 B (total ~26.5 MB)

    // prep (one launch) + CSR build with parallel scan
    k_prep<<<2048, 256, 0, stream>>>(cnt, W1a, w1a, W1e, w1e, W2a, w2a, W2e, w2e, nfeats, nfbf);
    k_count<<<1024, 256, 0, stream>>>(v, cnt);
    k_scanA<<<49, 1024, 0, stream>>>(cnt, bsum);
    k_scanB<<<1, 64, 0, stream>>>(bsum, boff, off);
    k_scanC<<<49, 1024, 0, stream>>>(cnt, boff, off, cur);
    k_fill<<<1024, 256, 0, stream>>>(u, v, cur, se);

    // layer 1
    k_agg1<<<NN / 4, 256, 0, stream>>>(nfbf, efeats, se, off, Xbuf);
    k_mlp_pq<0><<<(NN + 63) / 64, 256, 0, stream>>>(Xbuf, w1a, b1a, w1e, b1e, HP1, Q1, nullptr, nullptr, nullptr, NN);

    // layer 2 (layer-1 edge-MLP fused into aggregation)
    k_agg2<<<NN / 4, 256, 0, stream>>>(HP1, Q1, se, off, Xbuf);
    k_mlp_pq<1><<<(NN + 63) / 64, 256, 0, stream>>>(Xbuf, w2a, b2a, w2e, b2e, nullptr, nullptr, h2f, P2, Q2, NN);
    k_add2<<<NE / 64, 256, 0, stream>>>(P2, Q2, u, v, e2f);
}